// Round 12
// baseline (259.160 us; speedup 1.0000x reference)
//
#include <hip/hip_runtime.h>
#include <math.h>

#define EPSF 1e-8f
#define Tn 512
#define Dn 64
#define NELEM 65536
#define STL 513   // LDS sT stride in half8 units (conflict-free: 513*4 dwords % 32 = 4)

typedef _Float16 half_t;
typedef __attribute__((ext_vector_type(8))) _Float16 half8;

__device__ __forceinline__ float sigmoidf_(float x){ return 1.0f/(1.0f+__expf(-x)); }
__device__ __forceinline__ float softplusf_(float x){ return fmaxf(x,0.0f) + log1pf(__expf(-fabsf(x))); }

__device__ __forceinline__ float wrs(float v){
  #pragma unroll
  for (int off=1; off<64; off<<=1) v += __shfl_xor(v, off, 64);
  return v;
}
__device__ __forceinline__ float wrm(float v){
  #pragma unroll
  for (int off=1; off<64; off<<=1) v = fmaxf(v, __shfl_xor(v, off, 64));
  return v;
}

// pnorm for one row (one full wave). fp16 k8-major transposed stream ONLY:
// sTh[(b*8+k8)*512 + r] = half8 of dims 8k8..8k8+7 for row r.
__device__ __forceinline__ void pnorm_h(float xg, int b, int r, int lane,
                                        half_t* __restrict__ sTh){
  float s = softplusf_(xg);
  float sum = wrs(s);
  float p = fmaxf(s/(sum+EPSF), EPSF);
  float s2 = wrs(p);
  float sq = sqrtf(p/(s2+EPSF));
  float v[8];
  #pragma unroll
  for (int m=0;m<8;m++) v[m] = __shfl(sq, (lane&7)*8 + m, 64);
  if (lane < 8){
    half8 hv;
    #pragma unroll
    for (int m=0;m<8;m++) hv[m] = (half_t)v[m];
    ((half8*)sTh)[((size_t)b*8 + lane)*512 + r] = hv;
  }
}

// gate dot (NI=2): 8 threads per output d, each dots 16 of 128 (proven)
__device__ __forceinline__ void gate_dot2(float (*comb)[128], float* gred,
                                          const float* __restrict__ Wfb, int tid, int lane){
  int dd = tid >> 3, k8 = tid & 7;
  const float4* wp = (const float4*)(Wfb + (size_t)dd*128 + k8*16);
  float4 w0 = wp[0], w1 = wp[1], w2 = wp[2], w3 = wp[3];
  float ga[2];
  #pragma unroll
  for (int i=0;i<2;i++){
    float4 c0 = *(const float4*)&comb[i][k8*16];
    float4 c1 = *(const float4*)&comb[i][k8*16+4];
    float4 c2 = *(const float4*)&comb[i][k8*16+8];
    float4 c3 = *(const float4*)&comb[i][k8*16+12];
    ga[i] = w0.x*c0.x + w0.y*c0.y + w0.z*c0.z + w0.w*c0.w
          + w1.x*c1.x + w1.y*c1.y + w1.z*c1.z + w1.w*c1.w
          + w2.x*c2.x + w2.y*c2.y + w2.z*c2.z + w2.w*c2.w
          + w3.x*c3.x + w3.y*c3.y + w3.z*c3.z + w3.w*c3.w;
  }
  #pragma unroll
  for (int off=1; off<8; off<<=1){
    ga[0] += __shfl_xor(ga[0],off,64); ga[1] += __shfl_xor(ga[1],off,64);
  }
  if ((lane&7)==0){ gred[dd*3+0]=ga[0]; gred[dd*3+1]=ga[1]; }
}

// ---- Layer-0 kernel with fused prologue (v2: cooperative LDS pnorm, no scratch).
// Each wave computes wave-parallel pnorm for 64 rows of the block's batch and
// packs the fp16 k8-major stream into LDS (u.sT). Dot runs against LDS; PV reads
// basin_seq fp32. u.sT unions with pvp (dead after dot; softmax barriers separate).
// Block 0 publishes temps0 and zeroes pooled_g.
__global__ __launch_bounds__(512) void k_attn0(
    const float* __restrict__ basin_seq, const float* __restrict__ basin_coords,
    const float* __restrict__ W_temp, const float* __restrict__ b_temp,
    const float* __restrict__ res_scale,
    half_t* __restrict__ xh_out, half_t* __restrict__ sTh_out,
    float* __restrict__ temps_out, float* __restrict__ pooled_g){

  __shared__ __align__(16) union {
    half8 sT[8*STL];   // 65.7 KB: [k8][row] fp16 pnorm stream (dot phase)
    float pvp[64*64];  // 16 KB: PV partials (PV phase)
  } u;
  __shared__ __align__(16) float P[512*2];
  __shared__ __align__(16) float s01[128];
  __shared__ float redw[2][8][2];
  __shared__ float temps_l[4];

  int tid = threadIdx.x, wav = tid>>6, lane = tid&63;
  int row0 = blockIdx.x*2, b = row0>>9, rb = row0&511;
  int i_ = tid>>6, d_ = lane;

  // temps (every block computes; block 0 publishes)
  if (tid < 64){
    float cbv = basin_coords[tid];
    #pragma unroll
    for (int l2=0;l2<4;l2++){
      float v = wrs(W_temp[l2*Dn + tid]*cbv);
      if (tid==0) temps_l[l2] = sigmoidf_(v + b_temp[l2]) + 0.5f;
    }
  }
  if (blockIdx.x==0 && tid<128) pooled_g[tid] = 0.f;

  // cooperative pnorm of all 512 rows of batch b into u.sT (wave w: rows 64w..64w+63)
  {
    const float* xb = basin_seq + (size_t)b*Tn*Dn;
    for (int m=0; m<64; ++m){
      int r = wav*64 + m;
      float xv = xb[(size_t)r*Dn + lane];
      float s = softplusf_(xv);
      float sum = wrs(s);
      float p = fmaxf(s/(sum+EPSF), EPSF);
      float s2 = wrs(p);
      float sq = sqrtf(p/(s2+EPSF));
      float v[8];
      #pragma unroll
      for (int mm=0;mm<8;mm++) v[mm] = __shfl(sq, (lane&7)*8 + mm, 64);
      if (lane < 8){
        half8 hv;
        #pragma unroll
        for (int mm=0;mm<8;mm++) hv[mm] = (half_t)v[mm];
        u.sT[lane*STL + r] = hv;
      }
    }
  }
  // own-row init: wave-parallel pnorm of rows row0, row0+1 -> s01 (fp32)
  float xi_pre = 0.f;
  if (tid < 128){
    float xv = basin_seq[(size_t)(row0+i_)*Dn + d_];
    xi_pre = xv;
    float s = softplusf_(xv);
    float sum = wrs(s);
    float p = fmaxf(s/(sum+EPSF), EPSF);
    float s2 = wrs(p);
    s01[d_*2 + i_] = sqrtf(p/(s2+EPSF));
  }
  __syncthreads();
  if (blockIdx.x==0 && tid<4) temps_out[tid] = temps_l[tid];

  float invT = 1.0f/fmaxf(temps_l[0], 1e-6f);

  // dot from LDS stream: thread j = tid, 8 x ds_read_b128 conflict-free
  float a0=0.f, a1=0.f;
  {
    const float4* sp = (const float4*)s01;
    #pragma unroll
    for (int c8=0;c8<8;++c8){
      half8 kv = u.sT[c8*STL + tid];
      float kf[8];
      #pragma unroll
      for (int m=0;m<8;m++) kf[m] = (float)kv[m];
      #pragma unroll
      for (int q=0;q<4;q++){
        float4 sv = sp[c8*4+q];
        a0 = fmaf(kf[2*q],   sv.x, a0); a1 = fmaf(kf[2*q],   sv.y, a1);
        a0 = fmaf(kf[2*q+1], sv.z, a0); a1 = fmaf(kf[2*q+1], sv.w, a1);
      }
    }
  }
  // logits + softmax
  {
    float c0 = fminf(fmaxf(a0,-1.0f+1e-6f),1.0f-1e-6f);
    float c1 = fminf(fmaxf(a1,-1.0f+1e-6f),1.0f-1e-6f);
    float l0 = -2.0f*acosf(c0)*invT;
    float l1 = -2.0f*acosf(c1)*invT;
    float m0=wrm(l0), m1=wrm(l1);
    if (lane==0){ redw[0][wav][0]=m0; redw[0][wav][1]=m1; }
    __syncthreads();   // all dots complete beyond this point (u.sT dead)
    float mv0=redw[0][0][0], mv1=redw[0][0][1];
    #pragma unroll
    for (int w=1;w<8;w++){ mv0=fmaxf(mv0,redw[0][w][0]); mv1=fmaxf(mv1,redw[0][w][1]); }
    float e0=__expf(l0-mv0), e1=__expf(l1-mv1);
    *(float2*)&P[tid*2] = make_float2(e0,e1);
    float q0=wrs(e0), q1=wrs(e1);
    if (lane==0){ redw[1][wav][0]=q0; redw[1][wav][1]=q1; }
  }
  __syncthreads();
  // PV from basin_seq fp32 (proven round-2 pattern): thread (jg,dq), 16 j's
  {
    int jg = tid>>4, dq = tid&15;
    const float4* x4p = (const float4*)(basin_seq + (size_t)b*Tn*Dn);
    float4 o0={0,0,0,0}, o1={0,0,0,0};
    int jb = jg*16;
    #pragma unroll 8
    for (int jj=0; jj<16; ++jj){
      int j = jb + jj;
      float4 xv = x4p[(size_t)j*16 + dq];
      float2 pw = *(const float2*)&P[j*2];
      o0.x=fmaf(pw.x,xv.x,o0.x); o0.y=fmaf(pw.x,xv.y,o0.y);
      o0.z=fmaf(pw.x,xv.z,o0.z); o0.w=fmaf(pw.x,xv.w,o0.w);
      o1.x=fmaf(pw.y,xv.x,o1.x); o1.y=fmaf(pw.y,xv.y,o1.y);
      o1.z=fmaf(pw.y,xv.z,o1.z); o1.w=fmaf(pw.y,xv.w,o1.w);
    }
    *(float4*)&u.pvp[(jg*2+0)*64 + dq*4] = o0;
    *(float4*)&u.pvp[(jg*2+1)*64 + dq*4] = o1;
  }
  __syncthreads();
  // epilogue
  if (tid < 128){
    float ss = 0.f;
    #pragma unroll
    for (int g=0; g<32; ++g) ss += u.pvp[(g*2+i_)*64+d_];
    float sv2 = 0.f;
    #pragma unroll
    for (int w=0;w<8;w++) sv2 += redw[1][w][i_];
    float o = xi_pre + res_scale[0]*(ss/sv2 - xi_pre);
    xh_out[(size_t)(row0+i_)*Dn + d_] = (half_t)o;
    pnorm_h(o, b, rb+i_, lane, sTh_out);
  }
}

// ---- QFI attention chain kernel, fp16-only cross-boundary state.
// NI=2 rows/block, 512 blocks x 512 threads.
// MODE 0: standard (write xh + pnorm stream)
// MODE 1: L3 (write h3=fp16(o), pooled atomics, fused gate(o,prev=h0), write xh+pnorm)
// MODE 2: P1L0 (basin-MLP -> temps + publish, attn, gate(o,prev=h1), write xh+pnorm)
// MODE 3: P1 mid (attn, gate(o,prev), write xh+pnorm)
// MODE 4: final (out_f = o + 0.01*rsg*(o - basin_seq))
template<int MODE>
__global__ __launch_bounds__(512) void k_attn(
    const half_t* __restrict__ xh_in, const half_t* __restrict__ sTh_in,
    const float* __restrict__ temps_in, const float* __restrict__ res_scale, int l,
    half_t* __restrict__ xh_out, half_t* __restrict__ sTh_out,
    const float* __restrict__ Wfb, const float* __restrict__ bfb,
    const half_t* __restrict__ prevh,
    half_t* __restrict__ h3out, float* __restrict__ pooled_g, float* __restrict__ temps_out,
    const float* __restrict__ basin_coords,
    const float* __restrict__ Wc1, const float* __restrict__ bc1,
    const float* __restrict__ Wc2, const float* __restrict__ bc2,
    const float* __restrict__ Wu, const float* __restrict__ bu,
    const float* __restrict__ W_temp, const float* __restrict__ b_temp,
    const float* __restrict__ basin_seq, const float* __restrict__ rsg,
    float* __restrict__ out_f){

  __shared__ __align__(16) float pvp[128*64];   // 32 KB PV partials [(jg*2+i)][d]
  __shared__ __align__(16) float P[512*2];      // 4 KB exp weights [j][i]
  __shared__ __align__(16) float s01[128];      // [k][i] own-row pnorm
  __shared__ float redw[2][8][2];
  __shared__ __align__(16) float comb[2][128];
  __shared__ float gred[192];
  __shared__ float temps_l[4];
  __shared__ float pooled_l[128];
  __shared__ float h1l[64];
  __shared__ float hbl[128];
  __shared__ float combb[128];
  __shared__ float nb_l[64];

  int tid = threadIdx.x, wav = tid>>6, lane = tid&63;
  int row0 = blockIdx.x*2, b = row0>>9, rb = row0&511;
  int i_ = tid>>6, d_ = lane;   // epilogue mapping for tid<128

  // ---- MODE 2: redundant basin MLP from pooled_g -> temps_l (+ publish temps_p1)
  if constexpr (MODE == 2){
    if (tid < 128) pooled_l[tid] = pooled_g[tid];
    __syncthreads();
    if (tid < 64){
      int bb = tid>>5, h = tid&31;
      float acc=0.f;
      #pragma unroll 8
      for (int d2=0; d2<64; d2++) acc += pooled_l[bb*64+d2]*Wc1[h*64+d2];
      h1l[tid] = tanhf(acc + bc1[h]);
    }
    __syncthreads();
    if (tid < 128){
      int bb = tid>>6, d = tid&63;
      float acc=0.f;
      #pragma unroll 8
      for (int h2=0; h2<32; h2++) acc += h1l[bb*32+h2]*Wc2[d*32+h2];
      hbl[tid] = tanhf(acc + bc2[d]);
    }
    __syncthreads();
    if (tid < 64){
      combb[tid] = basin_coords[tid];
      combb[64+tid] = 0.5f*(hbl[tid] + hbl[64+tid]);
    }
    __syncthreads();
    if (tid < 64){
      float acc=0.f;
      #pragma unroll 8
      for (int k=0;k<128;k++) acc += Wu[tid*128+k]*combb[k];
      float g = sigmoidf_(acc + bu[tid]);
      nb_l[tid] = combb[tid]*(1.0f-g) + combb[64+tid]*g;
    }
    __syncthreads();
    if (tid < 64){
      float nb = nb_l[tid];
      #pragma unroll
      for (int l2=0;l2<4;l2++){
        float v = wrs(W_temp[l2*Dn + tid]*nb);
        if (tid==0) temps_l[l2] = sigmoidf_(v + b_temp[l2]) + 0.5f;
      }
    }
    __syncthreads();
    if (tid < 4) temps_out[tid] = temps_l[tid];
  }

  // ---- own-row init (fp16 sources only)
  float xi_pre = 0.f, prev_pre = 0.f;
  if (tid < 128){
    half8 hv = ((const half8*)sTh_in)[((size_t)b*8 + (d_>>3))*512 + (rb+i_)];
    s01[d_*2 + i_] = (float)hv[d_&7];
    xi_pre = (float)xh_in[(size_t)(row0+i_)*Dn + d_];
    if constexpr (MODE == 1 || MODE == 2 || MODE == 3)
      prev_pre = (float)prevh[(size_t)(row0+i_)*Dn + d_];
  }
  __syncthreads();

  float invT;
  if constexpr (MODE == 2) invT = 1.0f/fmaxf(temps_l[0], 1e-6f);
  else                     invT = 1.0f/fmaxf(temps_in[l], 1e-6f);

  // ---- dot: thread j = tid computes inner(i0,j), inner(i1,j); 8 x 16B coalesced loads
  float a0=0.f, a1=0.f;
  {
    const half8* sT8 = (const half8*)sTh_in + (size_t)b*8*512;
    const float4* sp = (const float4*)s01;
    #pragma unroll
    for (int c8=0;c8<8;++c8){
      half8 kv = sT8[(size_t)c8*512 + tid];
      float kf[8];
      #pragma unroll
      for (int m=0;m<8;m++) kf[m] = (float)kv[m];
      #pragma unroll
      for (int q=0;q<4;q++){
        float4 sv = sp[c8*4+q];
        a0 = fmaf(kf[2*q],   sv.x, a0); a1 = fmaf(kf[2*q],   sv.y, a1);
        a0 = fmaf(kf[2*q+1], sv.z, a0); a1 = fmaf(kf[2*q+1], sv.w, a1);
      }
    }
  }
  // ---- logits + softmax
  {
    float c0 = fminf(fmaxf(a0,-1.0f+1e-6f),1.0f-1e-6f);
    float c1 = fminf(fmaxf(a1,-1.0f+1e-6f),1.0f-1e-6f);
    float l0 = -2.0f*acosf(c0)*invT;
    float l1 = -2.0f*acosf(c1)*invT;
    float m0=wrm(l0), m1=wrm(l1);
    if (lane==0){ redw[0][wav][0]=m0; redw[0][wav][1]=m1; }
    __syncthreads();
    float mv0=redw[0][0][0], mv1=redw[0][0][1];
    #pragma unroll
    for (int w=1;w<8;w++){ mv0=fmaxf(mv0,redw[0][w][0]); mv1=fmaxf(mv1,redw[0][w][1]); }
    float e0=__expf(l0-mv0), e1=__expf(l1-mv1);
    *(float2*)&P[tid*2] = make_float2(e0,e1);
    float q0=wrs(e0), q1=wrs(e1);
    if (lane==0){ redw[1][wav][0]=q0; redw[1][wav][1]=q1; }
  }
  __syncthreads();
  // ---- PV: thread (jg, dq8); 8 j's (stride 64), half8 along d (16B coalesced)
  {
    int jg = tid>>3, dq8 = tid&7;
    const half8* x8 = (const half8*)(xh_in + (size_t)b*Tn*Dn);
    float o0[8], o1[8];
    #pragma unroll
    for (int m=0;m<8;m++){ o0[m]=0.f; o1[m]=0.f; }
    #pragma unroll
    for (int jj=0; jj<8; ++jj){
      int j = jj*64 + jg;
      half8 xv = x8[(size_t)j*8 + dq8];
      float2 pw = *(const float2*)&P[j*2];
      #pragma unroll
      for (int m=0;m<8;m++){
        float xf = (float)xv[m];
        o0[m] = fmaf(pw.x, xf, o0[m]);
        o1[m] = fmaf(pw.y, xf, o1[m]);
      }
    }
    float* p0 = &pvp[(jg*2+0)*64 + dq8*8];
    float* p1 = &pvp[(jg*2+1)*64 + dq8*8];
    *(float4*)p0     = make_float4(o0[0],o0[1],o0[2],o0[3]);
    *(float4*)(p0+4) = make_float4(o0[4],o0[5],o0[6],o0[7]);
    *(float4*)p1     = make_float4(o1[0],o1[1],o1[2],o1[3]);
    *(float4*)(p1+4) = make_float4(o1[4],o1[5],o1[6],o1[7]);
  }
  __syncthreads();
  // ---- epilogue reduce
  float o = 0.f;
  if (tid < 128){
    float ss = 0.f;
    #pragma unroll
    for (int g=0; g<64; ++g) ss += pvp[(g*2+i_)*64+d_];
    float sv = 0.f;
    #pragma unroll
    for (int w=0;w<8;w++) sv += redw[1][w][i_];
    o = xi_pre + res_scale[l]*(ss/sv - xi_pre);
  }

  if constexpr (MODE == 0){
    if (tid < 128){
      xh_out[(size_t)(row0+i_)*Dn + d_] = (half_t)o;
      pnorm_h(o, b, rb+i_, lane, sTh_out);
    }
  } else if constexpr (MODE == 4){
    if (tid < 128){
      float c = 0.01f * rsg[0];
      out_f[(size_t)(row0+i_)*Dn + d_] = o + c*(o - basin_seq[(size_t)(row0+i_)*Dn + d_]);
    }
  } else {
    // MODE 1/2/3: fused gate with prev; MODE 1 also writes h3 + pooled atomics
    if (tid < 128){
      if constexpr (MODE == 1) h3out[(size_t)(row0+i_)*Dn + d_] = (half_t)o;
      comb[i_][d_] = o;
      comb[i_][64+d_] = prev_pre;
    }
    __syncthreads();
    if constexpr (MODE == 1){
      if (tid < 64)
        atomicAdd(&pooled_g[b*Dn + tid], (comb[0][tid]+comb[1][tid]) * (1.0f/Tn));
    }
    gate_dot2(comb, gred, Wfb, tid, lane);
    __syncthreads();
    if (tid < 128){
      float g = sigmoidf_(gred[d_*3+i_] + bfb[d_]);
      float xg = o*g + prev_pre*(1.0f-g);
      xh_out[(size_t)(row0+i_)*Dn + d_] = (half_t)xg;
      pnorm_h(xg, b, rb+i_, lane, sTh_out);
    }
  }
}

extern "C" void kernel_launch(void* const* d_in, const int* in_sizes, int n_in,
                              void* d_out, int out_size, void* d_ws, size_t ws_size,
                              hipStream_t stream) {
  const float* basin_seq    = (const float*)d_in[0];
  const float* basin_coords = (const float*)d_in[1];
  const float* W_temp       = (const float*)d_in[2];
  const float* b_temp       = (const float*)d_in[3];
  const float* res_scale    = (const float*)d_in[4];
  const float* W_fb         = (const float*)d_in[5];
  const float* b_fb         = (const float*)d_in[6];
  const float* Wc1          = (const float*)d_in[7];
  const float* bc1          = (const float*)d_in[8];
  const float* Wc2          = (const float*)d_in[9];
  const float* bc2          = (const float*)d_in[10];
  const float* Wu           = (const float*)d_in[11];
  const float* bu           = (const float*)d_in[12];
  const float* rsg          = (const float*)d_in[13];
  float* out = (float*)d_out;
  float* ws  = (float*)d_ws;

  const size_t N = NELEM; // 65536 elements
  float* pooled   = ws;             // 128 floats
  float* temps0   = ws + 128;       // 4
  float* temps_p1 = ws + 136;       // 4
  half_t* hb   = (half_t*)(ws + 256);
  half_t* h0   = hb + 0*N;          // st0
  half_t* h1   = hb + 1*N;          // st1
  half_t* h2   = hb + 2*N;          // st2
  half_t* h3   = hb + 3*N;          // st3
  half_t* hA   = hb + 4*N;          // pass-1 ping
  half_t* hB   = hb + 5*N;          // pass-1 pong
  half_t* sThA = hb + 6*N;
  half_t* sThB = hb + 7*N;

  const int GA = 512;
  const size_t WFB = (size_t)Dn*2*Dn;  // 8192

  // 1. pass-0 L0 with fused prologue (cooperative LDS pnorm; publishes temps0, zeroes pooled)
  k_attn0<<<GA,512,0,stream>>>(basin_seq, basin_coords, W_temp, b_temp, res_scale,
                               h0, sThA, temps0, pooled);
  // 2-3. pass-0 L1..L2
  k_attn<0><<<GA,512,0,stream>>>(h0, sThA, temps0, res_scale, 1,
      h1, sThB, nullptr,nullptr,nullptr, nullptr,nullptr,nullptr,
      nullptr,nullptr,nullptr,nullptr,nullptr,nullptr,nullptr,nullptr,nullptr,nullptr,nullptr,nullptr);
  k_attn<0><<<GA,512,0,stream>>>(h1, sThB, temps0, res_scale, 2,
      h2, sThA, nullptr,nullptr,nullptr, nullptr,nullptr,nullptr,
      nullptr,nullptr,nullptr,nullptr,nullptr,nullptr,nullptr,nullptr,nullptr,nullptr,nullptr,nullptr);
  // 4. pass-0 L3 + pooled atomics + fused P1L0 gate(st3, st0)
  k_attn<1><<<GA,512,0,stream>>>(h2, sThA, temps0, res_scale, 3,
      hA, sThB, W_fb, b_fb, h0, h3, pooled, nullptr,
      nullptr,nullptr,nullptr,nullptr,nullptr,nullptr,nullptr,nullptr,nullptr,nullptr,nullptr,nullptr);
  // 5. P1 L0: basin MLP + attn + gate(o, st1)
  k_attn<2><<<GA,512,0,stream>>>(hA, sThB, nullptr, res_scale, 0,
      hB, sThA, W_fb + 1*WFB, b_fb + 1*Dn, h1, nullptr, pooled, temps_p1,
      basin_coords, Wc1, bc1, Wc2, bc2, Wu, bu, W_temp, b_temp, nullptr,nullptr,nullptr);
  // 6. P1 L1 + gate(o, st2)
  k_attn<3><<<GA,512,0,stream>>>(hB, sThA, temps_p1, res_scale, 1,
      hA, sThB, W_fb + 2*WFB, b_fb + 2*Dn, h2, nullptr,nullptr,nullptr,
      nullptr,nullptr,nullptr,nullptr,nullptr,nullptr,nullptr,nullptr,nullptr,nullptr,nullptr,nullptr);
  // 7. P1 L2 + gate(o, st3)
  k_attn<3><<<GA,512,0,stream>>>(hA, sThB, temps_p1, res_scale, 2,
      hB, sThA, W_fb + 3*WFB, b_fb + 3*Dn, h3, nullptr,nullptr,nullptr,
      nullptr,nullptr,nullptr,nullptr,nullptr,nullptr,nullptr,nullptr,nullptr,nullptr,nullptr,nullptr);
  // 8. P1 L3 + final residual
  k_attn<4><<<GA,512,0,stream>>>(hB, sThA, temps_p1, res_scale, 3,
      nullptr, nullptr, nullptr,nullptr,nullptr, nullptr,nullptr,nullptr,
      nullptr,nullptr,nullptr,nullptr,nullptr,nullptr,nullptr,nullptr,nullptr,
      basin_seq, rsg, out);
}

// Round 13
// 220.116 us; speedup vs baseline: 1.1774x; 1.1774x over previous
//
#include <hip/hip_runtime.h>
#include <math.h>

#define EPSF 1e-8f
#define Tn 512
#define Dn 64
#define NELEM 65536
#define STL 513   // LDS sT stride in half8 units

typedef _Float16 half_t;
typedef __attribute__((ext_vector_type(8))) _Float16 half8;

__device__ __forceinline__ float sigmoidf_(float x){ return 1.0f/(1.0f+__expf(-x)); }
__device__ __forceinline__ float softplusf_(float x){ return fmaxf(x,0.0f) + log1pf(__expf(-fabsf(x))); }

__device__ __forceinline__ float wrs(float v){
  #pragma unroll
  for (int off=1; off<64; off<<=1) v += __shfl_xor(v, off, 64);
  return v;
}
__device__ __forceinline__ float wrm(float v){
  #pragma unroll
  for (int off=1; off<64; off<<=1) v = fmaxf(v, __shfl_xor(v, off, 64));
  return v;
}

// pnorm for one row (one full wave). fp16 k8-major transposed stream ONLY:
// sTh[(b*8+k8)*512 + r] = half8 of dims 8k8..8k8+7 for row r.
__device__ __forceinline__ void pnorm_h(float xg, int b, int r, int lane,
                                        half_t* __restrict__ sTh){
  float s = softplusf_(xg);
  float sum = wrs(s);
  float p = fmaxf(s/(sum+EPSF), EPSF);
  float s2 = wrs(p);
  float sq = sqrtf(p/(s2+EPSF));
  float v[8];
  #pragma unroll
  for (int m=0;m<8;m++) v[m] = __shfl(sq, (lane&7)*8 + m, 64);
  if (lane < 8){
    half8 hv;
    #pragma unroll
    for (int m=0;m<8;m++) hv[m] = (half_t)v[m];
    ((half8*)sTh)[((size_t)b*8 + lane)*512 + r] = hv;
  }
}

// gate dot (NI=2): 8 threads per output d, each dots 16 of 128 (proven)
__device__ __forceinline__ void gate_dot2(float (*comb)[128], float* gred,
                                          const float* __restrict__ Wfb, int tid, int lane){
  int dd = tid >> 3, k8 = tid & 7;
  const float4* wp = (const float4*)(Wfb + (size_t)dd*128 + k8*16);
  float4 w0 = wp[0], w1 = wp[1], w2 = wp[2], w3 = wp[3];
  float ga[2];
  #pragma unroll
  for (int i=0;i<2;i++){
    float4 c0 = *(const float4*)&comb[i][k8*16];
    float4 c1 = *(const float4*)&comb[i][k8*16+4];
    float4 c2 = *(const float4*)&comb[i][k8*16+8];
    float4 c3 = *(const float4*)&comb[i][k8*16+12];
    ga[i] = w0.x*c0.x + w0.y*c0.y + w0.z*c0.z + w0.w*c0.w
          + w1.x*c1.x + w1.y*c1.y + w1.z*c1.z + w1.w*c1.w
          + w2.x*c2.x + w2.y*c2.y + w2.z*c2.z + w2.w*c2.w
          + w3.x*c3.x + w3.y*c3.y + w3.z*c3.z + w3.w*c3.w;
  }
  #pragma unroll
  for (int off=1; off<8; off<<=1){
    ga[0] += __shfl_xor(ga[0],off,64); ga[1] += __shfl_xor(ga[1],off,64);
  }
  if ((lane&7)==0){ gred[dd*3+0]=ga[0]; gred[dd*3+1]=ga[1]; }
}

// ---- Layer-0 kernel with fused prologue (v3: 8-lane-group parallel pnorm).
// Pass p, thread (row = p*64 + tid>>3, k8 = tid&7): loads dims 8k8..8k8+7 of its
// row, group-reduces sums via 3x shfl_xor(1,2,4), packs its half8 directly into
// u.sT[k8][row] (zero repack shuffles; conflict-free banks). 8 passes = 512 rows.
// Dot/softmax/PV identical to the verified round-12 code.
__global__ __launch_bounds__(512) void k_attn0(
    const float* __restrict__ basin_seq, const float* __restrict__ basin_coords,
    const float* __restrict__ W_temp, const float* __restrict__ b_temp,
    const float* __restrict__ res_scale,
    half_t* __restrict__ xh_out, half_t* __restrict__ sTh_out,
    float* __restrict__ temps_out, float* __restrict__ pooled_g){

  __shared__ __align__(16) union {
    half8 sT[8*STL];   // 65.7 KB: [k8][row] fp16 pnorm stream (dot phase)
    float pvp[64*64];  // 16 KB: PV partials (PV phase)
  } u;
  __shared__ __align__(16) float P[512*2];
  __shared__ __align__(16) float s01[128];
  __shared__ float redw[2][8][2];
  __shared__ float temps_l[4];

  int tid = threadIdx.x, wav = tid>>6, lane = tid&63;
  int row0 = blockIdx.x*2, b = row0>>9, rb = row0&511;
  int i_ = tid>>6, d_ = lane;

  // temps (every block computes; block 0 publishes)
  if (tid < 64){
    float cbv = basin_coords[tid];
    #pragma unroll
    for (int l2=0;l2<4;l2++){
      float v = wrs(W_temp[l2*Dn + tid]*cbv);
      if (tid==0) temps_l[l2] = sigmoidf_(v + b_temp[l2]) + 0.5f;
    }
  }
  if (blockIdx.x==0 && tid<128) pooled_g[tid] = 0.f;

  // group-parallel pnorm of all 512 rows of batch b into u.sT
  {
    const float* xb = basin_seq + (size_t)b*Tn*Dn;
    int rl = tid>>3, k8 = tid&7;
    #pragma unroll
    for (int p=0; p<8; ++p){
      int r = p*64 + rl;
      const float4* rp = (const float4*)(xb + (size_t)r*Dn + k8*8);
      float4 xa = rp[0], xb4 = rp[1];
      float sv0 = softplusf_(xa.x),  sv1 = softplusf_(xa.y);
      float sv2 = softplusf_(xa.z),  sv3 = softplusf_(xa.w);
      float sv4 = softplusf_(xb4.x), sv5 = softplusf_(xb4.y);
      float sv6 = softplusf_(xb4.z), sv7 = softplusf_(xb4.w);
      float ps = sv0+sv1+sv2+sv3+sv4+sv5+sv6+sv7;
      ps += __shfl_xor(ps,1,64); ps += __shfl_xor(ps,2,64); ps += __shfl_xor(ps,4,64);
      float inv1 = 1.0f/(ps+EPSF);
      sv0=fmaxf(sv0*inv1,EPSF); sv1=fmaxf(sv1*inv1,EPSF);
      sv2=fmaxf(sv2*inv1,EPSF); sv3=fmaxf(sv3*inv1,EPSF);
      sv4=fmaxf(sv4*inv1,EPSF); sv5=fmaxf(sv5*inv1,EPSF);
      sv6=fmaxf(sv6*inv1,EPSF); sv7=fmaxf(sv7*inv1,EPSF);
      float p2 = sv0+sv1+sv2+sv3+sv4+sv5+sv6+sv7;
      p2 += __shfl_xor(p2,1,64); p2 += __shfl_xor(p2,2,64); p2 += __shfl_xor(p2,4,64);
      float inv2 = 1.0f/(p2+EPSF);
      half8 hv;
      hv[0]=(half_t)sqrtf(sv0*inv2); hv[1]=(half_t)sqrtf(sv1*inv2);
      hv[2]=(half_t)sqrtf(sv2*inv2); hv[3]=(half_t)sqrtf(sv3*inv2);
      hv[4]=(half_t)sqrtf(sv4*inv2); hv[5]=(half_t)sqrtf(sv5*inv2);
      hv[6]=(half_t)sqrtf(sv6*inv2); hv[7]=(half_t)sqrtf(sv7*inv2);
      u.sT[k8*STL + r] = hv;
    }
  }
  // own-row init: wave-parallel pnorm of rows row0, row0+1 -> s01 (fp32)
  float xi_pre = 0.f;
  if (tid < 128){
    float xv = basin_seq[(size_t)(row0+i_)*Dn + d_];
    xi_pre = xv;
    float s = softplusf_(xv);
    float sum = wrs(s);
    float p = fmaxf(s/(sum+EPSF), EPSF);
    float s2 = wrs(p);
    s01[d_*2 + i_] = sqrtf(p/(s2+EPSF));
  }
  __syncthreads();
  if (blockIdx.x==0 && tid<4) temps_out[tid] = temps_l[tid];

  float invT = 1.0f/fmaxf(temps_l[0], 1e-6f);

  // dot from LDS stream: thread j = tid, 8 x ds_read_b128 conflict-free
  float a0=0.f, a1=0.f;
  {
    const float4* sp = (const float4*)s01;
    #pragma unroll
    for (int c8=0;c8<8;++c8){
      half8 kv = u.sT[c8*STL + tid];
      float kf[8];
      #pragma unroll
      for (int m=0;m<8;m++) kf[m] = (float)kv[m];
      #pragma unroll
      for (int q=0;q<4;q++){
        float4 sv = sp[c8*4+q];
        a0 = fmaf(kf[2*q],   sv.x, a0); a1 = fmaf(kf[2*q],   sv.y, a1);
        a0 = fmaf(kf[2*q+1], sv.z, a0); a1 = fmaf(kf[2*q+1], sv.w, a1);
      }
    }
  }
  // logits + softmax
  {
    float c0 = fminf(fmaxf(a0,-1.0f+1e-6f),1.0f-1e-6f);
    float c1 = fminf(fmaxf(a1,-1.0f+1e-6f),1.0f-1e-6f);
    float l0 = -2.0f*acosf(c0)*invT;
    float l1 = -2.0f*acosf(c1)*invT;
    float m0=wrm(l0), m1=wrm(l1);
    if (lane==0){ redw[0][wav][0]=m0; redw[0][wav][1]=m1; }
    __syncthreads();   // all dots complete beyond this point (u.sT dead)
    float mv0=redw[0][0][0], mv1=redw[0][0][1];
    #pragma unroll
    for (int w=1;w<8;w++){ mv0=fmaxf(mv0,redw[0][w][0]); mv1=fmaxf(mv1,redw[0][w][1]); }
    float e0=__expf(l0-mv0), e1=__expf(l1-mv1);
    *(float2*)&P[tid*2] = make_float2(e0,e1);
    float q0=wrs(e0), q1=wrs(e1);
    if (lane==0){ redw[1][wav][0]=q0; redw[1][wav][1]=q1; }
  }
  __syncthreads();
  // PV from basin_seq fp32 (proven round-2 pattern): thread (jg,dq), 16 j's
  {
    int jg = tid>>4, dq = tid&15;
    const float4* x4p = (const float4*)(basin_seq + (size_t)b*Tn*Dn);
    float4 o0={0,0,0,0}, o1={0,0,0,0};
    int jb = jg*16;
    #pragma unroll 8
    for (int jj=0; jj<16; ++jj){
      int j = jb + jj;
      float4 xv = x4p[(size_t)j*16 + dq];
      float2 pw = *(const float2*)&P[j*2];
      o0.x=fmaf(pw.x,xv.x,o0.x); o0.y=fmaf(pw.x,xv.y,o0.y);
      o0.z=fmaf(pw.x,xv.z,o0.z); o0.w=fmaf(pw.x,xv.w,o0.w);
      o1.x=fmaf(pw.y,xv.x,o1.x); o1.y=fmaf(pw.y,xv.y,o1.y);
      o1.z=fmaf(pw.y,xv.z,o1.z); o1.w=fmaf(pw.y,xv.w,o1.w);
    }
    *(float4*)&u.pvp[(jg*2+0)*64 + dq*4] = o0;
    *(float4*)&u.pvp[(jg*2+1)*64 + dq*4] = o1;
  }
  __syncthreads();
  // epilogue
  if (tid < 128){
    float ss = 0.f;
    #pragma unroll
    for (int g=0; g<32; ++g) ss += u.pvp[(g*2+i_)*64+d_];
    float sv2 = 0.f;
    #pragma unroll
    for (int w=0;w<8;w++) sv2 += redw[1][w][i_];
    float o = xi_pre + res_scale[0]*(ss/sv2 - xi_pre);
    xh_out[(size_t)(row0+i_)*Dn + d_] = (half_t)o;
    pnorm_h(o, b, rb+i_, lane, sTh_out);
  }
}

// ---- QFI attention chain kernel, fp16-only cross-boundary state.
// NI=2 rows/block, 512 blocks x 512 threads.
// MODE 0: standard (write xh + pnorm stream)
// MODE 1: L3 (write h3=fp16(o), pooled atomics, fused gate(o,prev=h0), write xh+pnorm)
// MODE 2: P1L0 (basin-MLP -> temps + publish, attn, gate(o,prev=h1), write xh+pnorm)
// MODE 3: P1 mid (attn, gate(o,prev), write xh+pnorm)
// MODE 4: final (out_f = o + 0.01*rsg*(o - basin_seq))
template<int MODE>
__global__ __launch_bounds__(512) void k_attn(
    const half_t* __restrict__ xh_in, const half_t* __restrict__ sTh_in,
    const float* __restrict__ temps_in, const float* __restrict__ res_scale, int l,
    half_t* __restrict__ xh_out, half_t* __restrict__ sTh_out,
    const float* __restrict__ Wfb, const float* __restrict__ bfb,
    const half_t* __restrict__ prevh,
    half_t* __restrict__ h3out, float* __restrict__ pooled_g, float* __restrict__ temps_out,
    const float* __restrict__ basin_coords,
    const float* __restrict__ Wc1, const float* __restrict__ bc1,
    const float* __restrict__ Wc2, const float* __restrict__ bc2,
    const float* __restrict__ Wu, const float* __restrict__ bu,
    const float* __restrict__ W_temp, const float* __restrict__ b_temp,
    const float* __restrict__ basin_seq, const float* __restrict__ rsg,
    float* __restrict__ out_f){

  __shared__ __align__(16) float pvp[128*64];   // 32 KB PV partials [(jg*2+i)][d]
  __shared__ __align__(16) float P[512*2];      // 4 KB exp weights [j][i]
  __shared__ __align__(16) float s01[128];      // [k][i] own-row pnorm
  __shared__ float redw[2][8][2];
  __shared__ __align__(16) float comb[2][128];
  __shared__ float gred[192];
  __shared__ float temps_l[4];
  __shared__ float pooled_l[128];
  __shared__ float h1l[64];
  __shared__ float hbl[128];
  __shared__ float combb[128];
  __shared__ float nb_l[64];

  int tid = threadIdx.x, wav = tid>>6, lane = tid&63;
  int row0 = blockIdx.x*2, b = row0>>9, rb = row0&511;
  int i_ = tid>>6, d_ = lane;   // epilogue mapping for tid<128

  // ---- MODE 2: redundant basin MLP from pooled_g -> temps_l (+ publish temps_p1)
  if constexpr (MODE == 2){
    if (tid < 128) pooled_l[tid] = pooled_g[tid];
    __syncthreads();
    if (tid < 64){
      int bb = tid>>5, h = tid&31;
      float acc=0.f;
      #pragma unroll 8
      for (int d2=0; d2<64; d2++) acc += pooled_l[bb*64+d2]*Wc1[h*64+d2];
      h1l[tid] = tanhf(acc + bc1[h]);
    }
    __syncthreads();
    if (tid < 128){
      int bb = tid>>6, d = tid&63;
      float acc=0.f;
      #pragma unroll 8
      for (int h2=0; h2<32; h2++) acc += h1l[bb*32+h2]*Wc2[d*32+h2];
      hbl[tid] = tanhf(acc + bc2[d]);
    }
    __syncthreads();
    if (tid < 64){
      combb[tid] = basin_coords[tid];
      combb[64+tid] = 0.5f*(hbl[tid] + hbl[64+tid]);
    }
    __syncthreads();
    if (tid < 64){
      float acc=0.f;
      #pragma unroll 8
      for (int k=0;k<128;k++) acc += Wu[tid*128+k]*combb[k];
      float g = sigmoidf_(acc + bu[tid]);
      nb_l[tid] = combb[tid]*(1.0f-g) + combb[64+tid]*g;
    }
    __syncthreads();
    if (tid < 64){
      float nb = nb_l[tid];
      #pragma unroll
      for (int l2=0;l2<4;l2++){
        float v = wrs(W_temp[l2*Dn + tid]*nb);
        if (tid==0) temps_l[l2] = sigmoidf_(v + b_temp[l2]) + 0.5f;
      }
    }
    __syncthreads();
    if (tid < 4) temps_out[tid] = temps_l[tid];
  }

  // ---- own-row init (fp16 sources only)
  float xi_pre = 0.f, prev_pre = 0.f;
  if (tid < 128){
    half8 hv = ((const half8*)sTh_in)[((size_t)b*8 + (d_>>3))*512 + (rb+i_)];
    s01[d_*2 + i_] = (float)hv[d_&7];
    xi_pre = (float)xh_in[(size_t)(row0+i_)*Dn + d_];
    if constexpr (MODE == 1 || MODE == 2 || MODE == 3)
      prev_pre = (float)prevh[(size_t)(row0+i_)*Dn + d_];
  }
  __syncthreads();

  float invT;
  if constexpr (MODE == 2) invT = 1.0f/fmaxf(temps_l[0], 1e-6f);
  else                     invT = 1.0f/fmaxf(temps_in[l], 1e-6f);

  // ---- dot: thread j = tid computes inner(i0,j), inner(i1,j); 8 x 16B coalesced loads
  float a0=0.f, a1=0.f;
  {
    const half8* sT8 = (const half8*)sTh_in + (size_t)b*8*512;
    const float4* sp = (const float4*)s01;
    #pragma unroll
    for (int c8=0;c8<8;++c8){
      half8 kv = sT8[(size_t)c8*512 + tid];
      float kf[8];
      #pragma unroll
      for (int m=0;m<8;m++) kf[m] = (float)kv[m];
      #pragma unroll
      for (int q=0;q<4;q++){
        float4 sv = sp[c8*4+q];
        a0 = fmaf(kf[2*q],   sv.x, a0); a1 = fmaf(kf[2*q],   sv.y, a1);
        a0 = fmaf(kf[2*q+1], sv.z, a0); a1 = fmaf(kf[2*q+1], sv.w, a1);
      }
    }
  }
  // ---- logits + softmax
  {
    float c0 = fminf(fmaxf(a0,-1.0f+1e-6f),1.0f-1e-6f);
    float c1 = fminf(fmaxf(a1,-1.0f+1e-6f),1.0f-1e-6f);
    float l0 = -2.0f*acosf(c0)*invT;
    float l1 = -2.0f*acosf(c1)*invT;
    float m0=wrm(l0), m1=wrm(l1);
    if (lane==0){ redw[0][wav][0]=m0; redw[0][wav][1]=m1; }
    __syncthreads();
    float mv0=redw[0][0][0], mv1=redw[0][0][1];
    #pragma unroll
    for (int w=1;w<8;w++){ mv0=fmaxf(mv0,redw[0][w][0]); mv1=fmaxf(mv1,redw[0][w][1]); }
    float e0=__expf(l0-mv0), e1=__expf(l1-mv1);
    *(float2*)&P[tid*2] = make_float2(e0,e1);
    float q0=wrs(e0), q1=wrs(e1);
    if (lane==0){ redw[1][wav][0]=q0; redw[1][wav][1]=q1; }
  }
  __syncthreads();
  // ---- PV: thread (jg, dq8); 8 j's (stride 64), half8 along d (16B coalesced)
  {
    int jg = tid>>3, dq8 = tid&7;
    const half8* x8 = (const half8*)(xh_in + (size_t)b*Tn*Dn);
    float o0[8], o1[8];
    #pragma unroll
    for (int m=0;m<8;m++){ o0[m]=0.f; o1[m]=0.f; }
    #pragma unroll
    for (int jj=0; jj<8; ++jj){
      int j = jj*64 + jg;
      half8 xv = x8[(size_t)j*8 + dq8];
      float2 pw = *(const float2*)&P[j*2];
      #pragma unroll
      for (int m=0;m<8;m++){
        float xf = (float)xv[m];
        o0[m] = fmaf(pw.x, xf, o0[m]);
        o1[m] = fmaf(pw.y, xf, o1[m]);
      }
    }
    float* p0 = &pvp[(jg*2+0)*64 + dq8*8];
    float* p1 = &pvp[(jg*2+1)*64 + dq8*8];
    *(float4*)p0     = make_float4(o0[0],o0[1],o0[2],o0[3]);
    *(float4*)(p0+4) = make_float4(o0[4],o0[5],o0[6],o0[7]);
    *(float4*)p1     = make_float4(o1[0],o1[1],o1[2],o1[3]);
    *(float4*)(p1+4) = make_float4(o1[4],o1[5],o1[6],o1[7]);
  }
  __syncthreads();
  // ---- epilogue reduce
  float o = 0.f;
  if (tid < 128){
    float ss = 0.f;
    #pragma unroll
    for (int g=0; g<64; ++g) ss += pvp[(g*2+i_)*64+d_];
    float sv = 0.f;
    #pragma unroll
    for (int w=0;w<8;w++) sv += redw[1][w][i_];
    o = xi_pre + res_scale[l]*(ss/sv - xi_pre);
  }

  if constexpr (MODE == 0){
    if (tid < 128){
      xh_out[(size_t)(row0+i_)*Dn + d_] = (half_t)o;
      pnorm_h(o, b, rb+i_, lane, sTh_out);
    }
  } else if constexpr (MODE == 4){
    if (tid < 128){
      float c = 0.01f * rsg[0];
      out_f[(size_t)(row0+i_)*Dn + d_] = o + c*(o - basin_seq[(size_t)(row0+i_)*Dn + d_]);
    }
  } else {
    // MODE 1/2/3: fused gate with prev; MODE 1 also writes h3 + pooled atomics
    if (tid < 128){
      if constexpr (MODE == 1) h3out[(size_t)(row0+i_)*Dn + d_] = (half_t)o;
      comb[i_][d_] = o;
      comb[i_][64+d_] = prev_pre;
    }
    __syncthreads();
    if constexpr (MODE == 1){
      if (tid < 64)
        atomicAdd(&pooled_g[b*Dn + tid], (comb[0][tid]+comb[1][tid]) * (1.0f/Tn));
    }
    gate_dot2(comb, gred, Wfb, tid, lane);
    __syncthreads();
    if (tid < 128){
      float g = sigmoidf_(gred[d_*3+i_] + bfb[d_]);
      float xg = o*g + prev_pre*(1.0f-g);
      xh_out[(size_t)(row0+i_)*Dn + d_] = (half_t)xg;
      pnorm_h(xg, b, rb+i_, lane, sTh_out);
    }
  }
}

extern "C" void kernel_launch(void* const* d_in, const int* in_sizes, int n_in,
                              void* d_out, int out_size, void* d_ws, size_t ws_size,
                              hipStream_t stream) {
  const float* basin_seq    = (const float*)d_in[0];
  const float* basin_coords = (const float*)d_in[1];
  const float* W_temp       = (const float*)d_in[2];
  const float* b_temp       = (const float*)d_in[3];
  const float* res_scale    = (const float*)d_in[4];
  const float* W_fb         = (const float*)d_in[5];
  const float* b_fb         = (const float*)d_in[6];
  const float* Wc1          = (const float*)d_in[7];
  const float* bc1          = (const float*)d_in[8];
  const float* Wc2          = (const float*)d_in[9];
  const float* bc2          = (const float*)d_in[10];
  const float* Wu           = (const float*)d_in[11];
  const float* bu           = (const float*)d_in[12];
  const float* rsg          = (const float*)d_in[13];
  float* out = (float*)d_out;
  float* ws  = (float*)d_ws;

  const size_t N = NELEM; // 65536 elements
  float* pooled   = ws;             // 128 floats
  float* temps0   = ws + 128;       // 4
  float* temps_p1 = ws + 136;       // 4
  half_t* hb   = (half_t*)(ws + 256);
  half_t* h0   = hb + 0*N;          // st0
  half_t* h1   = hb + 1*N;          // st1
  half_t* h2   = hb + 2*N;          // st2
  half_t* h3   = hb + 3*N;          // st3
  half_t* hA   = hb + 4*N;          // pass-1 ping
  half_t* hB   = hb + 5*N;          // pass-1 pong
  half_t* sThA = hb + 6*N;
  half_t* sThB = hb + 7*N;

  const int GA = 512;
  const size_t WFB = (size_t)Dn*2*Dn;  // 8192

  // 1. pass-0 L0 with fused prologue (group-parallel pnorm; publishes temps0, zeroes pooled)
  k_attn0<<<GA,512,0,stream>>>(basin_seq, basin_coords, W_temp, b_temp, res_scale,
                               h0, sThA, temps0, pooled);
  // 2-3. pass-0 L1..L2
  k_attn<0><<<GA,512,0,stream>>>(h0, sThA, temps0, res_scale, 1,
      h1, sThB, nullptr,nullptr,nullptr, nullptr,nullptr,nullptr,
      nullptr,nullptr,nullptr,nullptr,nullptr,nullptr,nullptr,nullptr,nullptr,nullptr,nullptr,nullptr);
  k_attn<0><<<GA,512,0,stream>>>(h1, sThB, temps0, res_scale, 2,
      h2, sThA, nullptr,nullptr,nullptr, nullptr,nullptr,nullptr,
      nullptr,nullptr,nullptr,nullptr,nullptr,nullptr,nullptr,nullptr,nullptr,nullptr,nullptr,nullptr);
  // 4. pass-0 L3 + pooled atomics + fused P1L0 gate(st3, st0)
  k_attn<1><<<GA,512,0,stream>>>(h2, sThA, temps0, res_scale, 3,
      hA, sThB, W_fb, b_fb, h0, h3, pooled, nullptr,
      nullptr,nullptr,nullptr,nullptr,nullptr,nullptr,nullptr,nullptr,nullptr,nullptr,nullptr,nullptr);
  // 5. P1 L0: basin MLP + attn + gate(o, st1)
  k_attn<2><<<GA,512,0,stream>>>(hA, sThB, nullptr, res_scale, 0,
      hB, sThA, W_fb + 1*WFB, b_fb + 1*Dn, h1, nullptr, pooled, temps_p1,
      basin_coords, Wc1, bc1, Wc2, bc2, Wu, bu, W_temp, b_temp, nullptr,nullptr,nullptr);
  // 6. P1 L1 + gate(o, st2)
  k_attn<3><<<GA,512,0,stream>>>(hB, sThA, temps_p1, res_scale, 1,
      hA, sThB, W_fb + 2*WFB, b_fb + 2*Dn, h2, nullptr,nullptr,nullptr,
      nullptr,nullptr,nullptr,nullptr,nullptr,nullptr,nullptr,nullptr,nullptr,nullptr,nullptr,nullptr);
  // 7. P1 L2 + gate(o, st3)
  k_attn<3><<<GA,512,0,stream>>>(hA, sThB, temps_p1, res_scale, 2,
      hB, sThA, W_fb + 3*WFB, b_fb + 3*Dn, h3, nullptr,nullptr,nullptr,
      nullptr,nullptr,nullptr,nullptr,nullptr,nullptr,nullptr,nullptr,nullptr,nullptr,nullptr,nullptr);
  // 8. P1 L3 + final residual
  k_attn<4><<<GA,512,0,stream>>>(hB, sThA, temps_p1, res_scale, 3,
      nullptr, nullptr, nullptr,nullptr,nullptr, nullptr,nullptr,nullptr,
      nullptr,nullptr,nullptr,nullptr,nullptr,nullptr,nullptr,nullptr,nullptr,
      basin_seq, rsg, out);
}

// Round 14
// 184.385 us; speedup vs baseline: 1.4055x; 1.1938x over previous
//
#include <hip/hip_runtime.h>
#include <math.h>

#define EPSF 1e-8f
#define Tn 512
#define Dn 64
#define NELEM 65536
#define STL 513   // LDS sT stride in half8 units

typedef _Float16 half_t;
typedef __attribute__((ext_vector_type(8))) _Float16 half8;

__device__ __forceinline__ float sigmoidf_(float x){ return 1.0f/(1.0f+__expf(-x)); }
__device__ __forceinline__ float softplusf_(float x){ return fmaxf(x,0.0f) + log1pf(__expf(-fabsf(x))); }
// fast softplus for the redundant all-rows path: __logf(1+e), e in (0,1] -> arg in (1,2],
// no cancellation; abs err <= ~1e-8, far below the fp16 carrier quantization.
__device__ __forceinline__ float softplus_fast(float x){ return fmaxf(x,0.0f) + __logf(1.0f+__expf(-fabsf(x))); }

__device__ __forceinline__ float wrs(float v){
  #pragma unroll
  for (int off=1; off<64; off<<=1) v += __shfl_xor(v, off, 64);
  return v;
}
__device__ __forceinline__ float wrm(float v){
  #pragma unroll
  for (int off=1; off<64; off<<=1) v = fmaxf(v, __shfl_xor(v, off, 64));
  return v;
}

// pnorm for one row (one full wave). fp16 k8-major transposed stream ONLY:
// sTh[(b*8+k8)*512 + r] = half8 of dims 8k8..8k8+7 for row r.
__device__ __forceinline__ void pnorm_h(float xg, int b, int r, int lane,
                                        half_t* __restrict__ sTh){
  float s = softplusf_(xg);
  float sum = wrs(s);
  float p = fmaxf(s/(sum+EPSF), EPSF);
  float s2 = wrs(p);
  float sq = sqrtf(p/(s2+EPSF));
  float v[8];
  #pragma unroll
  for (int m=0;m<8;m++) v[m] = __shfl(sq, (lane&7)*8 + m, 64);
  if (lane < 8){
    half8 hv;
    #pragma unroll
    for (int m=0;m<8;m++) hv[m] = (half_t)v[m];
    ((half8*)sTh)[((size_t)b*8 + lane)*512 + r] = hv;
  }
}

// gate dot (NI=2): 8 threads per output d, each dots 16 of 128 (proven)
__device__ __forceinline__ void gate_dot2(float (*comb)[128], float* gred,
                                          const float* __restrict__ Wfb, int tid, int lane){
  int dd = tid >> 3, k8 = tid & 7;
  const float4* wp = (const float4*)(Wfb + (size_t)dd*128 + k8*16);
  float4 w0 = wp[0], w1 = wp[1], w2 = wp[2], w3 = wp[3];
  float ga[2];
  #pragma unroll
  for (int i=0;i<2;i++){
    float4 c0 = *(const float4*)&comb[i][k8*16];
    float4 c1 = *(const float4*)&comb[i][k8*16+4];
    float4 c2 = *(const float4*)&comb[i][k8*16+8];
    float4 c3 = *(const float4*)&comb[i][k8*16+12];
    ga[i] = w0.x*c0.x + w0.y*c0.y + w0.z*c0.z + w0.w*c0.w
          + w1.x*c1.x + w1.y*c1.y + w1.z*c1.z + w1.w*c1.w
          + w2.x*c2.x + w2.y*c2.y + w2.z*c2.z + w2.w*c2.w
          + w3.x*c3.x + w3.y*c3.y + w3.z*c3.z + w3.w*c3.w;
  }
  #pragma unroll
  for (int off=1; off<8; off<<=1){
    ga[0] += __shfl_xor(ga[0],off,64); ga[1] += __shfl_xor(ga[1],off,64);
  }
  if ((lane&7)==0){ gred[dd*3+0]=ga[0]; gred[dd*3+1]=ga[1]; }
}

// ---- Layer-0 kernel with fused prologue (v4 = v3 + softplus_fast in hot loop).
// Pass p, thread (row = p*64 + tid>>3, k8 = tid&7): loads dims 8k8..8k8+7 of its
// row, group-reduces sums via 3x shfl_xor(1,2,4), packs its half8 directly into
// u.sT[k8][row]. 8 passes = 512 rows. Dot/softmax/PV identical to verified code.
__global__ __launch_bounds__(512) void k_attn0(
    const float* __restrict__ basin_seq, const float* __restrict__ basin_coords,
    const float* __restrict__ W_temp, const float* __restrict__ b_temp,
    const float* __restrict__ res_scale,
    half_t* __restrict__ xh_out, half_t* __restrict__ sTh_out,
    float* __restrict__ temps_out, float* __restrict__ pooled_g){

  __shared__ __align__(16) union {
    half8 sT[8*STL];   // 65.7 KB: [k8][row] fp16 pnorm stream (dot phase)
    float pvp[64*64];  // 16 KB: PV partials (PV phase)
  } u;
  __shared__ __align__(16) float P[512*2];
  __shared__ __align__(16) float s01[128];
  __shared__ float redw[2][8][2];
  __shared__ float temps_l[4];

  int tid = threadIdx.x, wav = tid>>6, lane = tid&63;
  int row0 = blockIdx.x*2, b = row0>>9, rb = row0&511;
  int i_ = tid>>6, d_ = lane;

  // temps (every block computes; block 0 publishes)
  if (tid < 64){
    float cbv = basin_coords[tid];
    #pragma unroll
    for (int l2=0;l2<4;l2++){
      float v = wrs(W_temp[l2*Dn + tid]*cbv);
      if (tid==0) temps_l[l2] = sigmoidf_(v + b_temp[l2]) + 0.5f;
    }
  }
  if (blockIdx.x==0 && tid<128) pooled_g[tid] = 0.f;

  // group-parallel pnorm of all 512 rows of batch b into u.sT (fast softplus)
  {
    const float* xb = basin_seq + (size_t)b*Tn*Dn;
    int rl = tid>>3, k8 = tid&7;
    #pragma unroll
    for (int p=0; p<8; ++p){
      int r = p*64 + rl;
      const float4* rp = (const float4*)(xb + (size_t)r*Dn + k8*8);
      float4 xa = rp[0], xb4 = rp[1];
      float sv0 = softplus_fast(xa.x),  sv1 = softplus_fast(xa.y);
      float sv2 = softplus_fast(xa.z),  sv3 = softplus_fast(xa.w);
      float sv4 = softplus_fast(xb4.x), sv5 = softplus_fast(xb4.y);
      float sv6 = softplus_fast(xb4.z), sv7 = softplus_fast(xb4.w);
      float ps = sv0+sv1+sv2+sv3+sv4+sv5+sv6+sv7;
      ps += __shfl_xor(ps,1,64); ps += __shfl_xor(ps,2,64); ps += __shfl_xor(ps,4,64);
      float inv1 = 1.0f/(ps+EPSF);
      sv0=fmaxf(sv0*inv1,EPSF); sv1=fmaxf(sv1*inv1,EPSF);
      sv2=fmaxf(sv2*inv1,EPSF); sv3=fmaxf(sv3*inv1,EPSF);
      sv4=fmaxf(sv4*inv1,EPSF); sv5=fmaxf(sv5*inv1,EPSF);
      sv6=fmaxf(sv6*inv1,EPSF); sv7=fmaxf(sv7*inv1,EPSF);
      float p2 = sv0+sv1+sv2+sv3+sv4+sv5+sv6+sv7;
      p2 += __shfl_xor(p2,1,64); p2 += __shfl_xor(p2,2,64); p2 += __shfl_xor(p2,4,64);
      float inv2 = 1.0f/(p2+EPSF);
      half8 hv;
      hv[0]=(half_t)sqrtf(sv0*inv2); hv[1]=(half_t)sqrtf(sv1*inv2);
      hv[2]=(half_t)sqrtf(sv2*inv2); hv[3]=(half_t)sqrtf(sv3*inv2);
      hv[4]=(half_t)sqrtf(sv4*inv2); hv[5]=(half_t)sqrtf(sv5*inv2);
      hv[6]=(half_t)sqrtf(sv6*inv2); hv[7]=(half_t)sqrtf(sv7*inv2);
      u.sT[k8*STL + r] = hv;
    }
  }
  // own-row init: wave-parallel pnorm of rows row0, row0+1 -> s01 (fp32, fast softplus
  // to match the u.sT entries this dots against)
  float xi_pre = 0.f;
  if (tid < 128){
    float xv = basin_seq[(size_t)(row0+i_)*Dn + d_];
    xi_pre = xv;
    float s = softplus_fast(xv);
    float sum = wrs(s);
    float p = fmaxf(s/(sum+EPSF), EPSF);
    float s2 = wrs(p);
    s01[d_*2 + i_] = sqrtf(p/(s2+EPSF));
  }
  __syncthreads();
  if (blockIdx.x==0 && tid<4) temps_out[tid] = temps_l[tid];

  float invT = 1.0f/fmaxf(temps_l[0], 1e-6f);

  // dot from LDS stream: thread j = tid, 8 x ds_read_b128
  float a0=0.f, a1=0.f;
  {
    const float4* sp = (const float4*)s01;
    #pragma unroll
    for (int c8=0;c8<8;++c8){
      half8 kv = u.sT[c8*STL + tid];
      float kf[8];
      #pragma unroll
      for (int m=0;m<8;m++) kf[m] = (float)kv[m];
      #pragma unroll
      for (int q=0;q<4;q++){
        float4 sv = sp[c8*4+q];
        a0 = fmaf(kf[2*q],   sv.x, a0); a1 = fmaf(kf[2*q],   sv.y, a1);
        a0 = fmaf(kf[2*q+1], sv.z, a0); a1 = fmaf(kf[2*q+1], sv.w, a1);
      }
    }
  }
  // logits + softmax
  {
    float c0 = fminf(fmaxf(a0,-1.0f+1e-6f),1.0f-1e-6f);
    float c1 = fminf(fmaxf(a1,-1.0f+1e-6f),1.0f-1e-6f);
    float l0 = -2.0f*acosf(c0)*invT;
    float l1 = -2.0f*acosf(c1)*invT;
    float m0=wrm(l0), m1=wrm(l1);
    if (lane==0){ redw[0][wav][0]=m0; redw[0][wav][1]=m1; }
    __syncthreads();   // all dots complete beyond this point (u.sT dead)
    float mv0=redw[0][0][0], mv1=redw[0][0][1];
    #pragma unroll
    for (int w=1;w<8;w++){ mv0=fmaxf(mv0,redw[0][w][0]); mv1=fmaxf(mv1,redw[0][w][1]); }
    float e0=__expf(l0-mv0), e1=__expf(l1-mv1);
    *(float2*)&P[tid*2] = make_float2(e0,e1);
    float q0=wrs(e0), q1=wrs(e1);
    if (lane==0){ redw[1][wav][0]=q0; redw[1][wav][1]=q1; }
  }
  __syncthreads();
  // PV from basin_seq fp32 (proven round-2 pattern): thread (jg,dq), 16 j's
  {
    int jg = tid>>4, dq = tid&15;
    const float4* x4p = (const float4*)(basin_seq + (size_t)b*Tn*Dn);
    float4 o0={0,0,0,0}, o1={0,0,0,0};
    int jb = jg*16;
    #pragma unroll 8
    for (int jj=0; jj<16; ++jj){
      int j = jb + jj;
      float4 xv = x4p[(size_t)j*16 + dq];
      float2 pw = *(const float2*)&P[j*2];
      o0.x=fmaf(pw.x,xv.x,o0.x); o0.y=fmaf(pw.x,xv.y,o0.y);
      o0.z=fmaf(pw.x,xv.z,o0.z); o0.w=fmaf(pw.x,xv.w,o0.w);
      o1.x=fmaf(pw.y,xv.x,o1.x); o1.y=fmaf(pw.y,xv.y,o1.y);
      o1.z=fmaf(pw.y,xv.z,o1.z); o1.w=fmaf(pw.y,xv.w,o1.w);
    }
    *(float4*)&u.pvp[(jg*2+0)*64 + dq*4] = o0;
    *(float4*)&u.pvp[(jg*2+1)*64 + dq*4] = o1;
  }
  __syncthreads();
  // epilogue
  if (tid < 128){
    float ss = 0.f;
    #pragma unroll
    for (int g=0; g<32; ++g) ss += u.pvp[(g*2+i_)*64+d_];
    float sv2 = 0.f;
    #pragma unroll
    for (int w=0;w<8;w++) sv2 += redw[1][w][i_];
    float o = xi_pre + res_scale[0]*(ss/sv2 - xi_pre);
    xh_out[(size_t)(row0+i_)*Dn + d_] = (half_t)o;
    pnorm_h(o, b, rb+i_, lane, sTh_out);
  }
}

// ---- QFI attention chain kernel, fp16-only cross-boundary state.
// NI=2 rows/block, 512 blocks x 512 threads.
// MODE 0: standard (write xh + pnorm stream)
// MODE 1: L3 (write h3=fp16(o), pooled atomics, fused gate(o,prev=h0), write xh+pnorm)
// MODE 2: P1L0 (basin-MLP -> temps + publish, attn, gate(o,prev=h1), write xh+pnorm)
// MODE 3: P1 mid (attn, gate(o,prev), write xh+pnorm)
// MODE 4: final (out_f = o + 0.01*rsg*(o - basin_seq))
template<int MODE>
__global__ __launch_bounds__(512) void k_attn(
    const half_t* __restrict__ xh_in, const half_t* __restrict__ sTh_in,
    const float* __restrict__ temps_in, const float* __restrict__ res_scale, int l,
    half_t* __restrict__ xh_out, half_t* __restrict__ sTh_out,
    const float* __restrict__ Wfb, const float* __restrict__ bfb,
    const half_t* __restrict__ prevh,
    half_t* __restrict__ h3out, float* __restrict__ pooled_g, float* __restrict__ temps_out,
    const float* __restrict__ basin_coords,
    const float* __restrict__ Wc1, const float* __restrict__ bc1,
    const float* __restrict__ Wc2, const float* __restrict__ bc2,
    const float* __restrict__ Wu, const float* __restrict__ bu,
    const float* __restrict__ W_temp, const float* __restrict__ b_temp,
    const float* __restrict__ basin_seq, const float* __restrict__ rsg,
    float* __restrict__ out_f){

  __shared__ __align__(16) float pvp[128*64];   // 32 KB PV partials [(jg*2+i)][d]
  __shared__ __align__(16) float P[512*2];      // 4 KB exp weights [j][i]
  __shared__ __align__(16) float s01[128];      // [k][i] own-row pnorm
  __shared__ float redw[2][8][2];
  __shared__ __align__(16) float comb[2][128];
  __shared__ float gred[192];
  __shared__ float temps_l[4];
  __shared__ float pooled_l[128];
  __shared__ float h1l[64];
  __shared__ float hbl[128];
  __shared__ float combb[128];
  __shared__ float nb_l[64];

  int tid = threadIdx.x, wav = tid>>6, lane = tid&63;
  int row0 = blockIdx.x*2, b = row0>>9, rb = row0&511;
  int i_ = tid>>6, d_ = lane;   // epilogue mapping for tid<128

  // ---- MODE 2: redundant basin MLP from pooled_g -> temps_l (+ publish temps_p1)
  if constexpr (MODE == 2){
    if (tid < 128) pooled_l[tid] = pooled_g[tid];
    __syncthreads();
    if (tid < 64){
      int bb = tid>>5, h = tid&31;
      float acc=0.f;
      #pragma unroll 8
      for (int d2=0; d2<64; d2++) acc += pooled_l[bb*64+d2]*Wc1[h*64+d2];
      h1l[tid] = tanhf(acc + bc1[h]);
    }
    __syncthreads();
    if (tid < 128){
      int bb = tid>>6, d = tid&63;
      float acc=0.f;
      #pragma unroll 8
      for (int h2=0; h2<32; h2++) acc += h1l[bb*32+h2]*Wc2[d*32+h2];
      hbl[tid] = tanhf(acc + bc2[d]);
    }
    __syncthreads();
    if (tid < 64){
      combb[tid] = basin_coords[tid];
      combb[64+tid] = 0.5f*(hbl[tid] + hbl[64+tid]);
    }
    __syncthreads();
    if (tid < 64){
      float acc=0.f;
      #pragma unroll 8
      for (int k=0;k<128;k++) acc += Wu[tid*128+k]*combb[k];
      float g = sigmoidf_(acc + bu[tid]);
      nb_l[tid] = combb[tid]*(1.0f-g) + combb[64+tid]*g;
    }
    __syncthreads();
    if (tid < 64){
      float nb = nb_l[tid];
      #pragma unroll
      for (int l2=0;l2<4;l2++){
        float v = wrs(W_temp[l2*Dn + tid]*nb);
        if (tid==0) temps_l[l2] = sigmoidf_(v + b_temp[l2]) + 0.5f;
      }
    }
    __syncthreads();
    if (tid < 4) temps_out[tid] = temps_l[tid];
  }

  // ---- own-row init (fp16 sources only)
  float xi_pre = 0.f, prev_pre = 0.f;
  if (tid < 128){
    half8 hv = ((const half8*)sTh_in)[((size_t)b*8 + (d_>>3))*512 + (rb+i_)];
    s01[d_*2 + i_] = (float)hv[d_&7];
    xi_pre = (float)xh_in[(size_t)(row0+i_)*Dn + d_];
    if constexpr (MODE == 1 || MODE == 2 || MODE == 3)
      prev_pre = (float)prevh[(size_t)(row0+i_)*Dn + d_];
  }
  __syncthreads();

  float invT;
  if constexpr (MODE == 2) invT = 1.0f/fmaxf(temps_l[0], 1e-6f);
  else                     invT = 1.0f/fmaxf(temps_in[l], 1e-6f);

  // ---- dot: thread j = tid computes inner(i0,j), inner(i1,j); 8 x 16B coalesced loads
  float a0=0.f, a1=0.f;
  {
    const half8* sT8 = (const half8*)sTh_in + (size_t)b*8*512;
    const float4* sp = (const float4*)s01;
    #pragma unroll
    for (int c8=0;c8<8;++c8){
      half8 kv = sT8[(size_t)c8*512 + tid];
      float kf[8];
      #pragma unroll
      for (int m=0;m<8;m++) kf[m] = (float)kv[m];
      #pragma unroll
      for (int q=0;q<4;q++){
        float4 sv = sp[c8*4+q];
        a0 = fmaf(kf[2*q],   sv.x, a0); a1 = fmaf(kf[2*q],   sv.y, a1);
        a0 = fmaf(kf[2*q+1], sv.z, a0); a1 = fmaf(kf[2*q+1], sv.w, a1);
      }
    }
  }
  // ---- logits + softmax
  {
    float c0 = fminf(fmaxf(a0,-1.0f+1e-6f),1.0f-1e-6f);
    float c1 = fminf(fmaxf(a1,-1.0f+1e-6f),1.0f-1e-6f);
    float l0 = -2.0f*acosf(c0)*invT;
    float l1 = -2.0f*acosf(c1)*invT;
    float m0=wrm(l0), m1=wrm(l1);
    if (lane==0){ redw[0][wav][0]=m0; redw[0][wav][1]=m1; }
    __syncthreads();
    float mv0=redw[0][0][0], mv1=redw[0][0][1];
    #pragma unroll
    for (int w=1;w<8;w++){ mv0=fmaxf(mv0,redw[0][w][0]); mv1=fmaxf(mv1,redw[0][w][1]); }
    float e0=__expf(l0-mv0), e1=__expf(l1-mv1);
    *(float2*)&P[tid*2] = make_float2(e0,e1);
    float q0=wrs(e0), q1=wrs(e1);
    if (lane==0){ redw[1][wav][0]=q0; redw[1][wav][1]=q1; }
  }
  __syncthreads();
  // ---- PV: thread (jg, dq8); 8 j's (stride 64), half8 along d (16B coalesced)
  {
    int jg = tid>>3, dq8 = tid&7;
    const half8* x8 = (const half8*)(xh_in + (size_t)b*Tn*Dn);
    float o0[8], o1[8];
    #pragma unroll
    for (int m=0;m<8;m++){ o0[m]=0.f; o1[m]=0.f; }
    #pragma unroll
    for (int jj=0; jj<8; ++jj){
      int j = jj*64 + jg;
      half8 xv = x8[(size_t)j*8 + dq8];
      float2 pw = *(const float2*)&P[j*2];
      #pragma unroll
      for (int m=0;m<8;m++){
        float xf = (float)xv[m];
        o0[m] = fmaf(pw.x, xf, o0[m]);
        o1[m] = fmaf(pw.y, xf, o1[m]);
      }
    }
    float* p0 = &pvp[(jg*2+0)*64 + dq8*8];
    float* p1 = &pvp[(jg*2+1)*64 + dq8*8];
    *(float4*)p0     = make_float4(o0[0],o0[1],o0[2],o0[3]);
    *(float4*)(p0+4) = make_float4(o0[4],o0[5],o0[6],o0[7]);
    *(float4*)p1     = make_float4(o1[0],o1[1],o1[2],o1[3]);
    *(float4*)(p1+4) = make_float4(o1[4],o1[5],o1[6],o1[7]);
  }
  __syncthreads();
  // ---- epilogue reduce
  float o = 0.f;
  if (tid < 128){
    float ss = 0.f;
    #pragma unroll
    for (int g=0; g<64; ++g) ss += pvp[(g*2+i_)*64+d_];
    float sv = 0.f;
    #pragma unroll
    for (int w=0;w<8;w++) sv += redw[1][w][i_];
    o = xi_pre + res_scale[l]*(ss/sv - xi_pre);
  }

  if constexpr (MODE == 0){
    if (tid < 128){
      xh_out[(size_t)(row0+i_)*Dn + d_] = (half_t)o;
      pnorm_h(o, b, rb+i_, lane, sTh_out);
    }
  } else if constexpr (MODE == 4){
    if (tid < 128){
      float c = 0.01f * rsg[0];
      out_f[(size_t)(row0+i_)*Dn + d_] = o + c*(o - basin_seq[(size_t)(row0+i_)*Dn + d_]);
    }
  } else {
    // MODE 1/2/3: fused gate with prev; MODE 1 also writes h3 + pooled atomics
    if (tid < 128){
      if constexpr (MODE == 1) h3out[(size_t)(row0+i_)*Dn + d_] = (half_t)o;
      comb[i_][d_] = o;
      comb[i_][64+d_] = prev_pre;
    }
    __syncthreads();
    if constexpr (MODE == 1){
      if (tid < 64)
        atomicAdd(&pooled_g[b*Dn + tid], (comb[0][tid]+comb[1][tid]) * (1.0f/Tn));
    }
    gate_dot2(comb, gred, Wfb, tid, lane);
    __syncthreads();
    if (tid < 128){
      float g = sigmoidf_(gred[d_*3+i_] + bfb[d_]);
      float xg = o*g + prev_pre*(1.0f-g);
      xh_out[(size_t)(row0+i_)*Dn + d_] = (half_t)xg;
      pnorm_h(xg, b, rb+i_, lane, sTh_out);
    }
  }
}

extern "C" void kernel_launch(void* const* d_in, const int* in_sizes, int n_in,
                              void* d_out, int out_size, void* d_ws, size_t ws_size,
                              hipStream_t stream) {
  const float* basin_seq    = (const float*)d_in[0];
  const float* basin_coords = (const float*)d_in[1];
  const float* W_temp       = (const float*)d_in[2];
  const float* b_temp       = (const float*)d_in[3];
  const float* res_scale    = (const float*)d_in[4];
  const float* W_fb         = (const float*)d_in[5];
  const float* b_fb         = (const float*)d_in[6];
  const float* Wc1          = (const float*)d_in[7];
  const float* bc1          = (const float*)d_in[8];
  const float* Wc2          = (const float*)d_in[9];
  const float* bc2          = (const float*)d_in[10];
  const float* Wu           = (const float*)d_in[11];
  const float* bu           = (const float*)d_in[12];
  const float* rsg          = (const float*)d_in[13];
  float* out = (float*)d_out;
  float* ws  = (float*)d_ws;

  const size_t N = NELEM; // 65536 elements
  float* pooled   = ws;             // 128 floats
  float* temps0   = ws + 128;       // 4
  float* temps_p1 = ws + 136;       // 4
  half_t* hb   = (half_t*)(ws + 256);
  half_t* h0   = hb + 0*N;          // st0
  half_t* h1   = hb + 1*N;          // st1
  half_t* h2   = hb + 2*N;          // st2
  half_t* h3   = hb + 3*N;          // st3
  half_t* hA   = hb + 4*N;          // pass-1 ping
  half_t* hB   = hb + 5*N;          // pass-1 pong
  half_t* sThA = hb + 6*N;
  half_t* sThB = hb + 7*N;

  const int GA = 512;
  const size_t WFB = (size_t)Dn*2*Dn;  // 8192

  // 1. pass-0 L0 with fused prologue (group-parallel fast pnorm; publishes temps0, zeroes pooled)
  k_attn0<<<GA,512,0,stream>>>(basin_seq, basin_coords, W_temp, b_temp, res_scale,
                               h0, sThA, temps0, pooled);
  // 2-3. pass-0 L1..L2
  k_attn<0><<<GA,512,0,stream>>>(h0, sThA, temps0, res_scale, 1,
      h1, sThB, nullptr,nullptr,nullptr, nullptr,nullptr,nullptr,
      nullptr,nullptr,nullptr,nullptr,nullptr,nullptr,nullptr,nullptr,nullptr,nullptr,nullptr,nullptr);
  k_attn<0><<<GA,512,0,stream>>>(h1, sThB, temps0, res_scale, 2,
      h2, sThA, nullptr,nullptr,nullptr, nullptr,nullptr,nullptr,
      nullptr,nullptr,nullptr,nullptr,nullptr,nullptr,nullptr,nullptr,nullptr,nullptr,nullptr,nullptr);
  // 4. pass-0 L3 + pooled atomics + fused P1L0 gate(st3, st0)
  k_attn<1><<<GA,512,0,stream>>>(h2, sThA, temps0, res_scale, 3,
      hA, sThB, W_fb, b_fb, h0, h3, pooled, nullptr,
      nullptr,nullptr,nullptr,nullptr,nullptr,nullptr,nullptr,nullptr,nullptr,nullptr,nullptr,nullptr);
  // 5. P1 L0: basin MLP + attn + gate(o, st1)
  k_attn<2><<<GA,512,0,stream>>>(hA, sThB, nullptr, res_scale, 0,
      hB, sThA, W_fb + 1*WFB, b_fb + 1*Dn, h1, nullptr, pooled, temps_p1,
      basin_coords, Wc1, bc1, Wc2, bc2, Wu, bu, W_temp, b_temp, nullptr,nullptr,nullptr);
  // 6. P1 L1 + gate(o, st2)
  k_attn<3><<<GA,512,0,stream>>>(hB, sThA, temps_p1, res_scale, 1,
      hA, sThB, W_fb + 2*WFB, b_fb + 2*Dn, h2, nullptr,nullptr,nullptr,
      nullptr,nullptr,nullptr,nullptr,nullptr,nullptr,nullptr,nullptr,nullptr,nullptr,nullptr,nullptr);
  // 7. P1 L2 + gate(o, st3)
  k_attn<3><<<GA,512,0,stream>>>(hA, sThB, temps_p1, res_scale, 2,
      hB, sThA, W_fb + 3*WFB, b_fb + 3*Dn, h3, nullptr,nullptr,nullptr,
      nullptr,nullptr,nullptr,nullptr,nullptr,nullptr,nullptr,nullptr,nullptr,nullptr,nullptr,nullptr);
  // 8. P1 L3 + final residual
  k_attn<4><<<GA,512,0,stream>>>(hB, sThA, temps_p1, res_scale, 3,
      nullptr, nullptr, nullptr,nullptr,nullptr, nullptr,nullptr,nullptr,
      nullptr,nullptr,nullptr,nullptr,nullptr,nullptr,nullptr,nullptr,nullptr,
      basin_seq, rsg, out);
}

// Round 15
// 168.507 us; speedup vs baseline: 1.5380x; 1.0942x over previous
//
#include <hip/hip_runtime.h>
#include <math.h>

#define EPSF 1e-8f
#define Tn 512
#define Dn 64
#define NELEM 65536

typedef _Float16 half_t;
typedef __attribute__((ext_vector_type(8))) _Float16 half8;

__device__ __forceinline__ float sigmoidf_(float x){ return 1.0f/(1.0f+__expf(-x)); }
__device__ __forceinline__ float softplusf_(float x){ return fmaxf(x,0.0f) + log1pf(__expf(-fabsf(x))); }

__device__ __forceinline__ float wrs(float v){
  #pragma unroll
  for (int off=1; off<64; off<<=1) v += __shfl_xor(v, off, 64);
  return v;
}
__device__ __forceinline__ float wrm(float v){
  #pragma unroll
  for (int off=1; off<64; off<<=1) v = fmaxf(v, __shfl_xor(v, off, 64));
  return v;
}

// pnorm for one row (one full wave). Writes fp32 sr row (coalesced) and the
// fp16 k8-major transposed stream: sTh[(b*8+k8)*512 + r] = half8 of dims 8k8..8k8+7.
__device__ __forceinline__ void pnorm_g(float xg, int b, int r, int lane,
                                        float* __restrict__ sr_row, half_t* __restrict__ sTh){
  float s = softplusf_(xg);
  float sum = wrs(s);
  float p = fmaxf(s/(sum+EPSF), EPSF);
  float s2 = wrs(p);
  float sq = sqrtf(p/(s2+EPSF));
  sr_row[lane] = sq;
  float v[8];
  #pragma unroll
  for (int m=0;m<8;m++) v[m] = __shfl(sq, (lane&7)*8 + m, 64);
  if (lane < 8){
    half8 hv;
    #pragma unroll
    for (int m=0;m<8;m++) hv[m] = (half_t)v[m];
    ((half8*)sTh)[((size_t)b*8 + lane)*512 + r] = hv;
  }
}

// gate dot (NI=2): 8 threads per output d, each dots 16 of 128 (proven)
__device__ __forceinline__ void gate_dot2(float (*comb)[128], float* gred,
                                          const float* __restrict__ Wfb, int tid, int lane){
  int dd = tid >> 3, k8 = tid & 7;
  const float4* wp = (const float4*)(Wfb + (size_t)dd*128 + k8*16);
  float4 w0 = wp[0], w1 = wp[1], w2 = wp[2], w3 = wp[3];
  float ga[2];
  #pragma unroll
  for (int i=0;i<2;i++){
    float4 c0 = *(const float4*)&comb[i][k8*16];
    float4 c1 = *(const float4*)&comb[i][k8*16+4];
    float4 c2 = *(const float4*)&comb[i][k8*16+8];
    float4 c3 = *(const float4*)&comb[i][k8*16+12];
    ga[i] = w0.x*c0.x + w0.y*c0.y + w0.z*c0.z + w0.w*c0.w
          + w1.x*c1.x + w1.y*c1.y + w1.z*c1.z + w1.w*c1.w
          + w2.x*c2.x + w2.y*c2.y + w2.z*c2.z + w2.w*c2.w
          + w3.x*c3.x + w3.y*c3.y + w3.z*c3.z + w3.w*c3.w;
  }
  #pragma unroll
  for (int off=1; off<8; off<<=1){
    ga[0] += __shfl_xor(ga[0],off,64); ga[1] += __shfl_xor(ga[1],off,64);
  }
  if ((lane&7)==0){ gred[dd*3+0]=ga[0]; gred[dd*3+1]=ga[1]; }
}

// ---- prologue: pnorm(basin_seq)+fp16 copy (blocks 0..255); temps + pooled-zero (block 256)
__global__ __launch_bounds__(256) void k_prologue(
    const float* __restrict__ basin_seq, float* __restrict__ srA, half_t* __restrict__ sThA,
    half_t* __restrict__ xh0,
    const float* __restrict__ W_temp, const float* __restrict__ b_temp,
    const float* __restrict__ cb0, float* __restrict__ temps0, float* __restrict__ pooled_g){
  int tid = threadIdx.x, wid = tid>>6, lane = tid&63;
  if (blockIdx.x < 256){
    int row = blockIdx.x*4 + wid;
    float xv = basin_seq[(size_t)row*Dn + lane];
    xh0[(size_t)row*Dn + lane] = (half_t)xv;
    pnorm_g(xv, row>>9, row&511, lane, srA + (size_t)row*Dn, sThA);
  } else {
    if (tid < 64){
      float cbv = cb0[tid];
      #pragma unroll
      for (int l=0;l<4;l++){
        float v = wrs(W_temp[l*Dn + tid]*cbv);
        if (tid==0) temps0[l] = sigmoidf_(v + b_temp[l]) + 0.5f;
      }
    }
    if (tid < 128) pooled_g[tid] = 0.f;
  }
}

// ---- QFI attention chain kernel. NI=2 rows/block, 512 blocks x 512 threads.
// MODE 0: standard (write x fp32+fp16 + pnorm)
// MODE 1: L3 (write st3, pooled atomics, fused P1L0 gate(st3,st0), pnorm)
// MODE 2: P1L0 (basin-MLP -> temps, write temps_p1, attn, gate(o,st1), pnorm)
// MODE 3: P1 mid (attn, gate(o,prev), pnorm)
// MODE 4: final (out = o + 0.01*rsg*(o - basin_seq))
template<int MODE>
__global__ __launch_bounds__(512) void k_attn(
    const float* __restrict__ xin, const half_t* __restrict__ xh_in,
    const float* __restrict__ sr_in, const half_t* __restrict__ sTh_in,
    const float* __restrict__ temps_in, const float* __restrict__ res_scale, int l,
    float* __restrict__ xout, half_t* __restrict__ xh_out,
    float* __restrict__ sr_out, half_t* __restrict__ sTh_out,
    const float* __restrict__ Wfb, const float* __restrict__ bfb,
    const float* __restrict__ prev,
    float* __restrict__ st3out, float* __restrict__ pooled_g, float* __restrict__ temps_out,
    const float* __restrict__ basin_coords,
    const float* __restrict__ Wc1, const float* __restrict__ bc1,
    const float* __restrict__ Wc2, const float* __restrict__ bc2,
    const float* __restrict__ Wu, const float* __restrict__ bu,
    const float* __restrict__ W_temp, const float* __restrict__ b_temp,
    const float* __restrict__ basin_seq, const float* __restrict__ rsg){

  __shared__ __align__(16) float pvp[128*64];   // 32 KB PV partials [(jg*2+i)][d]
  __shared__ __align__(16) float P[512*2];      // 4 KB exp weights [j][i]
  __shared__ __align__(16) float s01[128];      // [k][i] own-row pnorm fp32
  __shared__ float redw[2][8][2];
  __shared__ __align__(16) float comb[2][128];
  __shared__ float gred[192];
  __shared__ float temps_l[4];
  __shared__ float pooled_l[128];
  __shared__ float h1l[64];
  __shared__ float hbl[128];
  __shared__ float combb[128];
  __shared__ float nb_l[64];

  int tid = threadIdx.x, wav = tid>>6, lane = tid&63;
  int row0 = blockIdx.x*2, b = row0>>9, rb = row0&511;
  int i_ = tid>>6, d_ = lane;   // epilogue mapping for tid<128

  // ---- MODE 2: redundant basin MLP from pooled_g -> temps_l (+ publish temps_p1)
  if constexpr (MODE == 2){
    if (tid < 128) pooled_l[tid] = pooled_g[tid];
    __syncthreads();
    if (tid < 64){
      int bb = tid>>5, h = tid&31;
      float acc=0.f;
      #pragma unroll 8
      for (int d2=0; d2<64; d2++) acc += pooled_l[bb*64+d2]*Wc1[h*64+d2];
      h1l[tid] = tanhf(acc + bc1[h]);
    }
    __syncthreads();
    if (tid < 128){
      int bb = tid>>6, d = tid&63;
      float acc=0.f;
      #pragma unroll 8
      for (int h2=0; h2<32; h2++) acc += h1l[bb*32+h2]*Wc2[d*32+h2];
      hbl[tid] = tanhf(acc + bc2[d]);
    }
    __syncthreads();
    if (tid < 64){
      combb[tid] = basin_coords[tid];
      combb[64+tid] = 0.5f*(hbl[tid] + hbl[64+tid]);
    }
    __syncthreads();
    if (tid < 64){
      float acc=0.f;
      #pragma unroll 8
      for (int k=0;k<128;k++) acc += Wu[tid*128+k]*combb[k];
      float g = sigmoidf_(acc + bu[tid]);
      nb_l[tid] = combb[tid]*(1.0f-g) + combb[64+tid]*g;
    }
    __syncthreads();
    if (tid < 64){
      float nb = nb_l[tid];
      #pragma unroll
      for (int l2=0;l2<4;l2++){
        float v = wrs(W_temp[l2*Dn + tid]*nb);
        if (tid==0) temps_l[l2] = sigmoidf_(v + b_temp[l2]) + 0.5f;
      }
    }
    __syncthreads();
    if (tid < 4) temps_out[tid] = temps_l[tid];
  }

  // ---- own-row init
  float xi_pre = 0.f, prev_pre = 0.f;
  if (tid < 128){
    s01[d_*2 + i_] = sr_in[(size_t)(row0+i_)*Dn + d_];
    xi_pre = xin[(size_t)(row0+i_)*Dn + d_];
    if constexpr (MODE == 1 || MODE == 2 || MODE == 3)
      prev_pre = prev[(size_t)(row0+i_)*Dn + d_];
  }
  __syncthreads();

  float invT;
  if constexpr (MODE == 2) invT = 1.0f/fmaxf(temps_l[0], 1e-6f);
  else                     invT = 1.0f/fmaxf(temps_in[l], 1e-6f);

  // ---- dot: thread j = tid computes inner(i0,j), inner(i1,j); 8 x 16B coalesced loads
  float a0=0.f, a1=0.f;
  {
    const half8* sT8 = (const half8*)sTh_in + (size_t)b*8*512;
    const float4* sp = (const float4*)s01;
    #pragma unroll
    for (int c8=0;c8<8;++c8){
      half8 kv = sT8[(size_t)c8*512 + tid];
      float kf[8];
      #pragma unroll
      for (int m=0;m<8;m++) kf[m] = (float)kv[m];
      #pragma unroll
      for (int q=0;q<4;q++){
        float4 sv = sp[c8*4+q];
        a0 = fmaf(kf[2*q],   sv.x, a0); a1 = fmaf(kf[2*q],   sv.y, a1);
        a0 = fmaf(kf[2*q+1], sv.z, a0); a1 = fmaf(kf[2*q+1], sv.w, a1);
      }
    }
  }
  // ---- logits + softmax
  {
    float c0 = fminf(fmaxf(a0,-1.0f+1e-6f),1.0f-1e-6f);
    float c1 = fminf(fmaxf(a1,-1.0f+1e-6f),1.0f-1e-6f);
    float l0 = -2.0f*acosf(c0)*invT;
    float l1 = -2.0f*acosf(c1)*invT;
    float m0=wrm(l0), m1=wrm(l1);
    if (lane==0){ redw[0][wav][0]=m0; redw[0][wav][1]=m1; }
    __syncthreads();
    float mv0=redw[0][0][0], mv1=redw[0][0][1];
    #pragma unroll
    for (int w=1;w<8;w++){ mv0=fmaxf(mv0,redw[0][w][0]); mv1=fmaxf(mv1,redw[0][w][1]); }
    float e0=__expf(l0-mv0), e1=__expf(l1-mv1);
    *(float2*)&P[tid*2] = make_float2(e0,e1);
    float q0=wrs(e0), q1=wrs(e1);
    if (lane==0){ redw[1][wav][0]=q0; redw[1][wav][1]=q1; }
  }
  __syncthreads();
  // ---- PV: thread (jg, dq8); 8 j's (stride 64), half8 along d (16B coalesced)
  {
    int jg = tid>>3, dq8 = tid&7;
    const half8* x8 = (const half8*)(xh_in + (size_t)b*Tn*Dn);
    float o0[8], o1[8];
    #pragma unroll
    for (int m=0;m<8;m++){ o0[m]=0.f; o1[m]=0.f; }
    #pragma unroll
    for (int jj=0; jj<8; ++jj){
      int j = jj*64 + jg;
      half8 xv = x8[(size_t)j*8 + dq8];
      float2 pw = *(const float2*)&P[j*2];
      #pragma unroll
      for (int m=0;m<8;m++){
        float xf = (float)xv[m];
        o0[m] = fmaf(pw.x, xf, o0[m]);
        o1[m] = fmaf(pw.y, xf, o1[m]);
      }
    }
    float* p0 = &pvp[(jg*2+0)*64 + dq8*8];
    float* p1 = &pvp[(jg*2+1)*64 + dq8*8];
    *(float4*)p0     = make_float4(o0[0],o0[1],o0[2],o0[3]);
    *(float4*)(p0+4) = make_float4(o0[4],o0[5],o0[6],o0[7]);
    *(float4*)p1     = make_float4(o1[0],o1[1],o1[2],o1[3]);
    *(float4*)(p1+4) = make_float4(o1[4],o1[5],o1[6],o1[7]);
  }
  __syncthreads();
  // ---- epilogue reduce
  float o = 0.f;
  if (tid < 128){
    float ss = 0.f;
    #pragma unroll
    for (int g=0; g<64; ++g) ss += pvp[(g*2+i_)*64+d_];
    float sv = 0.f;
    #pragma unroll
    for (int w=0;w<8;w++) sv += redw[1][w][i_];
    o = xi_pre + res_scale[l]*(ss/sv - xi_pre);
  }

  if constexpr (MODE == 0){
    if (tid < 128){
      xout[(size_t)(row0+i_)*Dn + d_] = o;
      xh_out[(size_t)(row0+i_)*Dn + d_] = (half_t)o;
      pnorm_g(o, b, rb+i_, lane, sr_out + (size_t)(row0+i_)*Dn, sTh_out);
    }
  } else if constexpr (MODE == 4){
    if (tid < 128){
      float c = 0.01f * rsg[0];
      xout[(size_t)(row0+i_)*Dn + d_] = o + c*(o - basin_seq[(size_t)(row0+i_)*Dn + d_]);
    }
  } else {
    // MODE 1/2/3: fused gate with prev; MODE 1 also writes st3 + pooled atomics
    if (tid < 128){
      if constexpr (MODE == 1) st3out[(size_t)(row0+i_)*Dn + d_] = o;
      comb[i_][d_] = o;
      comb[i_][64+d_] = prev_pre;
    }
    __syncthreads();
    if constexpr (MODE == 1){
      if (tid < 64)
        atomicAdd(&pooled_g[b*Dn + tid], (comb[0][tid]+comb[1][tid]) * (1.0f/Tn));
    }
    gate_dot2(comb, gred, Wfb, tid, lane);
    __syncthreads();
    if (tid < 128){
      float g = sigmoidf_(gred[d_*3+i_] + bfb[d_]);
      float xg = o*g + prev_pre*(1.0f-g);
      xout[(size_t)(row0+i_)*Dn + d_] = xg;
      xh_out[(size_t)(row0+i_)*Dn + d_] = (half_t)xg;
      pnorm_g(xg, b, rb+i_, lane, sr_out + (size_t)(row0+i_)*Dn, sTh_out);
    }
  }
}

extern "C" void kernel_launch(void* const* d_in, const int* in_sizes, int n_in,
                              void* d_out, int out_size, void* d_ws, size_t ws_size,
                              hipStream_t stream) {
  const float* basin_seq    = (const float*)d_in[0];
  const float* basin_coords = (const float*)d_in[1];
  const float* W_temp       = (const float*)d_in[2];
  const float* b_temp       = (const float*)d_in[3];
  const float* res_scale    = (const float*)d_in[4];
  const float* W_fb         = (const float*)d_in[5];
  const float* b_fb         = (const float*)d_in[6];
  const float* Wc1          = (const float*)d_in[7];
  const float* bc1          = (const float*)d_in[8];
  const float* Wc2          = (const float*)d_in[9];
  const float* bc2          = (const float*)d_in[10];
  const float* Wu           = (const float*)d_in[11];
  const float* bu           = (const float*)d_in[12];
  const float* rsg          = (const float*)d_in[13];
  float* out = (float*)d_out;
  float* ws  = (float*)d_ws;

  const size_t N = NELEM; // 65536
  float* srA      = ws;
  float* srB      = ws + N;
  float* st0      = ws + 2*N;
  float* st1      = ws + 3*N;
  float* st2      = ws + 4*N;
  float* st3      = ws + 5*N;
  float* xA       = ws + 6*N;
  float* xB       = ws + 7*N;
  float* pooled   = ws + 8*N;          // 128
  float* temps0   = ws + 8*N + 128;    // 4
  float* temps_p1 = ws + 8*N + 136;    // 4
  half_t* hbase = (half_t*)(ws + 8*N + 256);
  half_t* xh0  = hbase;                //  65536 halves each
  half_t* xhA  = hbase + 1*(size_t)N;
  half_t* xhB  = hbase + 2*(size_t)N;
  half_t* sThA = hbase + 3*(size_t)N;
  half_t* sThB = hbase + 4*(size_t)N;

  const int GA = 512;
  const size_t WFB = (size_t)Dn*2*Dn;  // 8192

  // 1. prologue
  k_prologue<<<257,256,0,stream>>>(basin_seq, srA, sThA, xh0,
                                   W_temp, b_temp, basin_coords, temps0, pooled);
  // 2-4. pass-0 L0..L2
  k_attn<0><<<GA,512,0,stream>>>(basin_seq, xh0, srA, sThA, temps0, res_scale, 0,
      st0, xhA, srB, sThB, nullptr,nullptr,nullptr, nullptr,nullptr,nullptr,
      nullptr,nullptr,nullptr,nullptr,nullptr,nullptr,nullptr,nullptr,nullptr,nullptr,nullptr);
  k_attn<0><<<GA,512,0,stream>>>(st0, xhA, srB, sThB, temps0, res_scale, 1,
      st1, xhB, srA, sThA, nullptr,nullptr,nullptr, nullptr,nullptr,nullptr,
      nullptr,nullptr,nullptr,nullptr,nullptr,nullptr,nullptr,nullptr,nullptr,nullptr,nullptr);
  k_attn<0><<<GA,512,0,stream>>>(st1, xhB, srA, sThA, temps0, res_scale, 2,
      st2, xhA, srB, sThB, nullptr,nullptr,nullptr, nullptr,nullptr,nullptr,
      nullptr,nullptr,nullptr,nullptr,nullptr,nullptr,nullptr,nullptr,nullptr,nullptr,nullptr);
  // 5. pass-0 L3 + pooled atomics + fused P1L0 gate(st3, st0)
  k_attn<1><<<GA,512,0,stream>>>(st2, xhA, srB, sThB, temps0, res_scale, 3,
      xA, xhB, srA, sThA, W_fb, b_fb, st0, st3, pooled, nullptr,
      nullptr,nullptr,nullptr,nullptr,nullptr,nullptr,nullptr,nullptr,nullptr,nullptr,nullptr);
  // 6. P1 L0: basin MLP + attn + gate(o, st1)
  k_attn<2><<<GA,512,0,stream>>>(xA, xhB, srA, sThA, nullptr, res_scale, 0,
      xB, xhA, srB, sThB, W_fb + 1*WFB, b_fb + 1*Dn, st1, nullptr, pooled, temps_p1,
      basin_coords, Wc1, bc1, Wc2, bc2, Wu, bu, W_temp, b_temp, nullptr,nullptr);
  // 7. P1 L1 + gate(o, st2)
  k_attn<3><<<GA,512,0,stream>>>(xB, xhA, srB, sThB, temps_p1, res_scale, 1,
      xA, xhB, srA, sThA, W_fb + 2*WFB, b_fb + 2*Dn, st2, nullptr,nullptr,nullptr,
      nullptr,nullptr,nullptr,nullptr,nullptr,nullptr,nullptr,nullptr,nullptr,nullptr,nullptr);
  // 8. P1 L2 + gate(o, st3)
  k_attn<3><<<GA,512,0,stream>>>(xA, xhB, srA, sThA, temps_p1, res_scale, 2,
      xB, xhA, srB, sThB, W_fb + 3*WFB, b_fb + 3*Dn, st3, nullptr,nullptr,nullptr,
      nullptr,nullptr,nullptr,nullptr,nullptr,nullptr,nullptr,nullptr,nullptr,nullptr,nullptr);
  // 9. P1 L3 + final residual
  k_attn<4><<<GA,512,0,stream>>>(xB, xhA, srB, sThB, temps_p1, res_scale, 3,
      out, nullptr, nullptr, nullptr, nullptr,nullptr,nullptr, nullptr,nullptr,nullptr,
      nullptr,nullptr,nullptr,nullptr,nullptr,nullptr,nullptr,nullptr,nullptr, basin_seq, rsg);
}